// Round 1
// baseline (956.368 us; speedup 1.0000x reference)
//
#include <hip/hip_runtime.h>
#include <hip/hip_fp16.h>
#include <math.h>

// Problem constants
#define NN   20000     // nodes
#define NE   320000    // edges
#define NIN  128       // node input dim
#define HC   256       // heads(4) * hidden(64)
#define NB   1024      // fused GEMM output width: [q | kv-interleaved | qproj]

#define AGG_BLOCKS 2048
#define AGG_WAVES  (AGG_BLOCKS * 4)
#define LOG2E_8    0.18033688f   // log2(e)/8 -- folds the 1/sqrt(64) scale + exp->exp2

typedef unsigned short u16;
typedef __attribute__((ext_vector_type(8))) short bf16x8;
typedef __attribute__((ext_vector_type(8))) unsigned short u16x8;
typedef __attribute__((ext_vector_type(4))) float f32x4;

__device__ __forceinline__ float bf2f(u16 u) {
  union { unsigned int i; float f; } x;
  x.i = ((unsigned int)u) << 16;
  return x.f;
}
__device__ __forceinline__ u16 f2bf(float f) {
  union { float f; unsigned int i; } x;
  x.f = f;
  unsigned int r = x.i + 0x7fffu + ((x.i >> 16) & 1u);
  return (u16)(r >> 16);
}
// packed-pair bf16 unpack: lo = <<16, hi = mask (1 VALU op each)
__device__ __forceinline__ float bflo(int v) {
  union { int i; float f; } x; x.i = v << 16; return x.f;
}
__device__ __forceinline__ float bfhi(int v) {
  union { int i; float f; } x; x.i = v & 0xffff0000; return x.f;
}

// dtype-flexible loads (flags detected on device each launch)
__device__ __forceinline__ float ldf(const void* p, int i, bool fbf) {
  return fbf ? bf2f(((const u16*)p)[i]) : ((const float*)p)[i];
}
__device__ __forceinline__ int ldsrc(const void* p, int e, bool is64) {
  const int* p32 = (const int*)p;
  return is64 ? p32[2 * e] : p32[e];
}
__device__ __forceinline__ int lddst(const void* p, int e, bool is64) {
  const int* p32 = (const int*)p;
  return is64 ? p32[2 * (NE + e)] : p32[NE + e];
}
__device__ __forceinline__ void stout(void* p, int i, float v, bool fbf) {
  if (fbf) ((u16*)p)[i] = f2bf(v);
  else ((float*)p)[i] = v;
}

// async global->LDS, 16B per lane
__device__ __forceinline__ void gload_lds16(const u16* g, u16* l) {
  __builtin_amdgcn_global_load_lds(
      (const __attribute__((address_space(1))) void*)g,
      (__attribute__((address_space(3))) void*)l, 16, 0, 0);
}

// 16-lane (row) all-sum via DPP row_ror adds: pure VALU, replaces 4 ds_bpermute.
// row_ror:N ctrl = 0x120|N. Sum over ror 1,2,4,8 gives every lane the full row sum.
__device__ __forceinline__ float dpp_row_allsum(float s) {
  union fi { float f; int i; };
  fi a, b;
  a.f = s;
  b.i = __builtin_amdgcn_update_dpp(0, a.i, 0x121, 0xf, 0xf, true); a.f += b.f;
  b.i = __builtin_amdgcn_update_dpp(0, a.i, 0x122, 0xf, 0xf, true); a.f += b.f;
  b.i = __builtin_amdgcn_update_dpp(0, a.i, 0x124, 0xf, 0xf, true); a.f += b.f;
  b.i = __builtin_amdgcn_update_dpp(0, a.i, 0x128, 0xf, 0xf, true); a.f += b.f;
  return a.f;
}

__device__ __forceinline__ float fexp2(float x) {
#if __has_builtin(__builtin_amdgcn_exp2f)
  return __builtin_amdgcn_exp2f(x);
#else
  return exp2f(x);
#endif
}

#if __has_builtin(__builtin_amdgcn_fdot2_f32_bf16)
#define HAS_BF16_DOT2 1
typedef __attribute__((ext_vector_type(2))) __bf16 bfv2_t;
__device__ __forceinline__ float qkdot2(int a, int b, float c) {
  return __builtin_amdgcn_fdot2_f32_bf16(__builtin_bit_cast(bfv2_t, a),
                                         __builtin_bit_cast(bfv2_t, b), c, false);
}
#else
#define HAS_BF16_DOT2 0
#endif

// one edge: alpha partial -> row reduce -> exp2 -> accumulate (no max tracking;
// |alpha| <= ~3 by construction, f32 exp safe by a huge margin)
__device__ __forceinline__ void edge_do(int4 kv, int2 t, int2 q2,
    float qsx, float qsy, float qsz, float qsw,
    float px, float py, float pz, float pw, float qb,
    float& denom, float& a0, float& a1, float& a2, float& a3) {
  float2 f01 = __half22float2(__builtin_bit_cast(__half2, t.x));
  float2 f23 = __half22float2(__builtin_bit_cast(__half2, t.y));
  float stp = f01.x * px + f01.y * py + f23.x * pz + f23.y * pw;
#if HAS_BF16_DOT2
  float sqk = qkdot2(kv.y, q2.y, qkdot2(kv.x, q2.x, 0.f));
  float partial = sqk * LOG2E_8 + stp;
#else
  float partial = stp + qsx * bflo(kv.x) + qsy * bfhi(kv.x) +
                  qsz * bflo(kv.y) + qsw * bfhi(kv.y);
#endif
  float a = dpp_row_allsum(partial) + qb;
  float ea = fexp2(a);
  denom += ea;
  a0 = fmaf(ea, bflo(kv.z), a0);
  a1 = fmaf(ea, bfhi(kv.z), a1);
  a2 = fmaf(ea, bflo(kv.w), a2);
  a3 = fmaf(ea, bfhi(kv.w), a3);
}

// ---------------- detection + div_term init + work-queue counters ----------------
__global__ void devinit_kernel(const void* __restrict__ eidx,
                               const void* __restrict__ nemb,
                               int* __restrict__ flags, float* __restrict__ divt) {
  int lane = threadIdx.x;
  if (lane < 32) {
    const float c32 = (float)(-0.14391156831212787);
    float prod = (float)(2 * lane) * c32;
    divt[lane] = (float)exp((double)prod);
  }
  if (lane == 0) {
    const int* p32 = (const int*)eidx;
    int is64 = 1;
    for (int i = 1; i < 128; i += 2)
      if (p32[i] != 0) { is64 = 0; break; }
    const u16* q16 = (const u16*)nemb;
    int fbf = 1;
    for (int i = 0; i < 128; i += 2) {
      unsigned e = (q16[i] >> 7) & 0xFF;
      if (e < 90 || e > 140) { fbf = 0; break; }
    }
    flags[0] = is64;
    flags[1] = fbf;
    flags[2] = AGG_WAVES;   // layer-1 node work-queue cursor
    flags[3] = AGG_WAVES;   // layer-2 node work-queue cursor
  }
}

__global__ void sentinel_kernel(const int* __restrict__ flags, void* __restrict__ out) {
  int i = blockIdx.x * 256 + threadIdx.x;
  if (i < NE) stout(out, i, 3000.0f, flags[1] != 0);
}
__global__ void raw_sentinel_kernel(u16* __restrict__ out) {
  int i = blockIdx.x * 256 + threadIdx.x;
  if (i < NE) out[i] = f2bf(3000.0f);
}

// ---------------- CSR build ----------------
__global__ void zero_kernel(int* __restrict__ p, int n) {
  int i = blockIdx.x * 256 + threadIdx.x;
  if (i < n) p[i] = 0;
}

__global__ void hist_kernel(const int* __restrict__ flags, const void* __restrict__ eidx,
                            int* __restrict__ cnt) {
  bool is64 = flags[0] != 0;
  int e = blockIdx.x * 256 + threadIdx.x;
  if (e < NE) {
    int d = lddst(eidx, e, is64);
    if ((unsigned)d < NN) atomicAdd(&cnt[d], 1);
  }
}

__global__ void scan1_kernel(const int* __restrict__ cnt, int* __restrict__ offs,
                             int* __restrict__ bsum, int n) {
  __shared__ int s[256];
  int b = blockIdx.x, t = threadIdx.x, i = b * 256 + t;
  int x = (i < n) ? cnt[i] : 0;
  s[t] = x;
  __syncthreads();
  for (int off = 1; off < 256; off <<= 1) {
    int y = (t >= off) ? s[t - off] : 0;
    __syncthreads();
    s[t] += y;
    __syncthreads();
  }
  if (i < n) offs[i] = s[t] - x;
  if (t == 255) bsum[b] = s[t];
}

__global__ void scan2_kernel(int* __restrict__ bsum, int* __restrict__ offs,
                             int nb, int n) {
  __shared__ int s[256];
  int t = threadIdx.x;
  int x = (t < nb) ? bsum[t] : 0;
  s[t] = x;
  __syncthreads();
  for (int off = 1; off < 256; off <<= 1) {
    int y = (t >= off) ? s[t - off] : 0;
    __syncthreads();
    s[t] += y;
    __syncthreads();
  }
  if (t < nb) bsum[t] = s[t] - x;
  if (t == 255) offs[n] = s[t];
}

__global__ void scan3_kernel(int* __restrict__ offs, const int* __restrict__ bsum,
                             int* __restrict__ cursor, int n) {
  int i = blockIdx.x * 256 + threadIdx.x;
  if (i < n) {
    int v = offs[i] + bsum[blockIdx.x];
    offs[i] = v;
    cursor[i] = v;
  }
}

__global__ void fill_kernel(const int* __restrict__ flags, const void* __restrict__ eidx,
                            const void* __restrict__ rawt, const void* __restrict__ noise,
                            int* __restrict__ cursor, int* __restrict__ ssrc,
                            float* __restrict__ stt) {
  bool is64 = flags[0] != 0, fbf = flags[1] != 0;
  int e = blockIdx.x * 256 + threadIdx.x;
  if (e < NE) {
    int d = lddst(eidx, e, is64);
    if ((unsigned)d < NN) {
      int pos = atomicAdd(&cursor[d], 1);
      if ((unsigned)pos < NE) {
        int src = ldsrc(eidx, e, is64);
        if ((unsigned)src >= NN) src = 0;
        ssrc[pos] = src;
        stt[pos] = ldf(rawt, e, fbf) + ldf(noise, e, fbf);
      }
    }
  }
}

// ---------------- te_s[p][64] (f16) — double range reduction + HW sin/cos --------
// v_sin_f32 / v_cos_f32 take REVOLUTIONS: feed the [0,1) fraction directly,
// skipping libm sincosf's second range reduction. HW error << f16 quantization.
__global__ __launch_bounds__(256) void te_kernel(
    const float* __restrict__ stt, const float* __restrict__ divt,
    u16* __restrict__ te_s) {
  int idx = blockIdx.x * 256 + threadIdx.x;
  int p = idx >> 5;          // 32 freqs per edge
  if (p >= NE) return;
  int f = idx & 31;
  float tt = stt[p];
  float arg = tt * divt[f];
  double rev = (double)arg * 0.15915494309189535;   // /(2π)
  double fr = rev - floor(rev);                     // [0,1) revolutions
  float frf = (float)fr;
  float sv = __builtin_amdgcn_sinf(frf);            // sin(2π·frf)
  float cv = __builtin_amdgcn_cosf(frf);            // cos(2π·frf)
  __half hs = __float2half(sv), hc = __float2half(cv);
  unsigned int packed = (unsigned int)(*(u16*)&hs) | ((unsigned int)(*(u16*)&hc) << 16);
  ((unsigned int*)te_s)[(size_t)p * 32 + f] = packed;
}

// ---------------- merged weight transpose: 3 matrices -> WtBig rows 0/256/512 -----
__global__ void transw3_kernel(const int* __restrict__ flags, const void* __restrict__ W0,
                               const void* __restrict__ W1, const void* __restrict__ W2,
                               u16* __restrict__ WtBig, int K) {
  bool fbf = flags[1] != 0;
  __shared__ u16 tile[64][65];
  int z = blockIdx.z;
  const void* W = (z == 0) ? W0 : (z == 1) ? W1 : W2;
  u16* dst = WtBig + (size_t)z * 256 * K;
  int kb = blockIdx.x * 64, cb = blockIdx.y * 64;
  int tx = threadIdx.x & 63, ty = threadIdx.x >> 6;
  for (int i = ty; i < 64; i += 4)
    tile[tx][i] = f2bf(ldf(W, (kb + i) * HC + cb + tx, fbf));
  __syncthreads();
  for (int i = ty; i < 64; i += 4)
    dst[(size_t)(cb + i) * K + kb + tx] = tile[i][tx];
}

// ---------------- wcomb + biasBig merged ----------------
__global__ void wcombbias_kernel(const int* __restrict__ flags, const void* __restrict__ wt,
                                 const u16* __restrict__ Wqt, u16* __restrict__ Wout,
                                 const void* __restrict__ bq, const void* __restrict__ bk,
                                 const void* __restrict__ bv, float* __restrict__ biasBig,
                                 int K) {
  bool fbf = flags[1] != 0;
  int b = blockIdx.x, t = threadIdx.x;
  if (b < 256) {
    __shared__ float wrow[64];
    int j = b, h = j >> 6;
    if (t < 64) wrow[t] = ldf(wt, (j & 63) * HC + h * 64 + t, fbf);
    __syncthreads();
    if (t < K) {
      float s = 0.f;
#pragma unroll 8
      for (int mm = 0; mm < 64; ++mm)
        s += wrow[mm] * bf2f(Wqt[(size_t)(h * 64 + mm) * K + t]);
      Wout[(size_t)j * K + t] = f2bf(s);
    }
  } else if (b < 259) {
    int bb = b - 256;
    const void* p = (bb == 0) ? bq : (bb == 1) ? bk : bv;
    biasBig[bb * 256 + t] = ldf(p, t, fbf);
  } else {
    int j = t, h = j >> 6;
    float s = 0.f;
    for (int mm = 0; mm < 64; ++mm)
      s += ldf(bq, h * 64 + mm, fbf) * ldf(wt, (j & 63) * HC + h * 64 + mm, fbf);
    biasBig[768 + j] = s;
  }
}

// ---------------- fused MFMA GEMM — 128x128 tile (m97-style) ----------------------
template <bool AWS>
__global__ __launch_bounds__(256) void gemm_mfma(
    const int* __restrict__ flags, const void* __restrict__ Ap,
    const u16* __restrict__ Wt, const float* __restrict__ bias,
    u16* __restrict__ C, int M, int K) {
  bool fbf = flags[1] != 0;
  __shared__ u16 As[128 * 32];
  __shared__ u16 Bs[128 * 32];
  int tid = threadIdx.x;
  int rb = blockIdx.x * 128, cb = blockIdx.y * 128;
  int wave = tid >> 6, lane = tid & 63;
  int l15 = lane & 15, quad = lane >> 4;
  int mbase = (wave >> 1) * 64, nbase = (wave & 1) * 64;

  f32x4 acc[4][4];
#pragma unroll
  for (int mt = 0; mt < 4; ++mt)
#pragma unroll
    for (int nt = 0; nt < 4; ++nt)
#pragma unroll
      for (int r = 0; r < 4; ++r) acc[mt][nt][r] = 0.f;

  int srow0 = tid >> 2, schunk0 = tid & 3;
  int srow1 = (tid + 256) >> 2, schunk1 = (tid + 256) & 3;
  int gchunk0 = schunk0 ^ (srow0 & 3);
  int gchunk1 = schunk1 ^ (srow1 & 3);
  int arow0 = rb + srow0; if (arow0 >= M) arow0 = M - 1;
  int arow1 = rb + srow1; if (arow1 >= M) arow1 = M - 1;
  u16* asl0 = &As[srow0 * 32 + schunk0 * 8];
  u16* asl1 = &As[srow1 * 32 + schunk1 * 8];
  u16* bsl0 = &Bs[srow0 * 32 + schunk0 * 8];
  u16* bsl1 = &Bs[srow1 * 32 + schunk1 * 8];
  const u16* bsrc0 = Wt + (size_t)(cb + srow0) * K + gchunk0 * 8;
  const u16* bsrc1 = Wt + (size_t)(cb + srow1) * K + gchunk1 * 8;
  const bool adirect = AWS || fbf;
  const u16* asrc0 = adirect ? ((const u16*)Ap + (size_t)arow0 * K + gchunk0 * 8) : (const u16*)0;
  const u16* asrc1 = adirect ? ((const u16*)Ap + (size_t)arow1 * K + gchunk1 * 8) : (const u16*)0;

  for (int kk = 0; kk < K; kk += 32) {
    if (adirect) {
      gload_lds16(asrc0 + kk, asl0);
      gload_lds16(asrc1 + kk, asl1);
    } else {
      const float* A0 = (const float*)Ap + (size_t)arow0 * K + kk + gchunk0 * 8;
      const float* A1 = (const float*)Ap + (size_t)arow1 * K + kk + gchunk1 * 8;
      bf16x8 t0, t1;
#pragma unroll
      for (int i = 0; i < 8; ++i) { t0[i] = (short)f2bf(A0[i]); t1[i] = (short)f2bf(A1[i]); }
      *(bf16x8*)asl0 = t0;
      *(bf16x8*)asl1 = t1;
    }
    gload_lds16(bsrc0 + kk, bsl0);
    gload_lds16(bsrc1 + kk, bsl1);
    __syncthreads();

    bf16x8 bfrag[4];
#pragma unroll
    for (int nt = 0; nt < 4; ++nt) {
      int col = nbase + nt * 16 + l15;
      bfrag[nt] = *(const bf16x8*)&Bs[col * 32 + ((quad ^ (col & 3)) * 8)];
    }
#pragma unroll
    for (int mt = 0; mt < 4; ++mt) {
      int row = mbase + mt * 16 + l15;
      bf16x8 afrag = *(const bf16x8*)&As[row * 32 + ((quad ^ (row & 3)) * 8)];
#pragma unroll
      for (int nt = 0; nt < 4; ++nt)
        acc[mt][nt] = __builtin_amdgcn_mfma_f32_16x16x32_bf16(afrag, bfrag[nt], acc[mt][nt], 0, 0, 0);
    }
    __syncthreads();
  }

#pragma unroll
  for (int nt = 0; nt < 4; ++nt) {
    int gcol = cb + nbase + nt * 16 + l15;
    float bv = bias[gcol];
    int scol;
    if (gcol < 256) scol = gcol;
    else if (gcol < 512) { int cc = gcol - 256; scol = 256 + ((cc >> 2) << 3) + (cc & 3); }
    else if (gcol < 768) { int cc = gcol - 512; scol = 256 + ((cc >> 2) << 3) + 4 + (cc & 3); }
    else scol = gcol;
#pragma unroll
    for (int mt = 0; mt < 4; ++mt) {
#pragma unroll
      for (int r = 0; r < 4; ++r) {
        int grow = rb + mbase + mt * 16 + quad * 4 + r;
        if (grow < M) C[(size_t)grow * NB + scol] = f2bf(acc[mt][nt][r] + bv);
      }
    }
  }
}

// ---------------- fused alpha + softmax + aggregation + relu -----------------------
// v2: dynamic node work-queue (atomic cursor, 1-node prefetch pipeline), DPP
// row-rotate reduce (no DS shuffles), no max tracking (|alpha| small -> direct
// exp2 with log2e/8 folded into p/qb), packed bf16 unpack, optional bf16 dot2.
template <int DOY>
__global__ __launch_bounds__(256, 4) void aggfused_kernel(
    const int* __restrict__ flags, const int* __restrict__ ssrc,
    const int* __restrict__ offsets, const u16* __restrict__ te_s,
    const u16* __restrict__ qkvp, const void* __restrict__ bt,
    u16* __restrict__ xout, const void* __restrict__ wc,
    float* __restrict__ ynode, int* __restrict__ qctr) {
  bool fbf = flags[1] != 0;
  int lane = threadIdx.x & 63;
  int c = lane * 4;
  int jb = c & 63;
  int kvoff = 256 + lane * 8;

  // node-invariant per-lane data
  float btv0 = ldf(bt, c + 0, fbf), btv1 = ldf(bt, c + 1, fbf);
  float btv2 = ldf(bt, c + 2, fbf), btv3 = ldf(bt, c + 3, fbf);
  float wcv0 = 0.f, wcv1 = 0.f, wcv2 = 0.f, wcv3 = 0.f;
  if (DOY) {
    wcv0 = ldf(wc, c + 0, fbf); wcv1 = ldf(wc, c + 1, fbf);
    wcv2 = ldf(wc, c + 2, fbf); wcv3 = ldf(wc, c + 3, fbf);
  }

  // first node: static = global wave id; prefetch its data
  int n = blockIdx.x * 4 + (threadIdx.x >> 6);
  int s0 = offsets[n], s1 = offsets[n + 1];
  int2 q2 = *(const int2*)(qkvp + (size_t)n * NB + c);
  int2 p2 = *(const int2*)(qkvp + (size_t)n * NB + 768 + c);
  int pg = NN;
  if (lane == 0) pg = atomicAdd(qctr, 1);   // grab for node #2

  while (n < NN) {
    // grab node #(i+2); resolve node #(i+1) from last iteration's grab
    int gnew = NN;
    if (lane == 0) gnew = atomicAdd(qctr, 1);
    int n1 = __builtin_amdgcn_readfirstlane(pg);
    int n1c = (n1 < NN) ? n1 : 0;
    // issue next-node prefetch (lands while we process node n)
    int s0n = offsets[n1c], s1n = offsets[n1c + 1];
    int2 q2n = *(const int2*)(qkvp + (size_t)n1c * NB + c);
    int2 p2n = *(const int2*)(qkvp + (size_t)n1c * NB + 768 + c);

    // ---- process node n (data already resident) ----
    float qx = bflo(q2.x), qy = bfhi(q2.x), qz = bflo(q2.y), qw = bfhi(q2.y);
    float px = bflo(p2.x) * LOG2E_8, py = bfhi(p2.x) * LOG2E_8;
    float pz = bflo(p2.y) * LOG2E_8, pw = bfhi(p2.y) * LOG2E_8;
    float pb = qx * btv0 + qy * btv1 + qz * btv2 + qw * btv3;
    float qb = dpp_row_allsum(pb) * LOG2E_8;
    float qsx = qx * LOG2E_8, qsy = qy * LOG2E_8;
    float qsz = qz * LOG2E_8, qsw = qw * LOG2E_8;

    float denom = 0.f, acc0 = 0.f, acc1 = 0.f, acc2 = 0.f, acc3 = 0.f;
    const int* sp = ssrc + s0;
    const u16* tep = te_s + (size_t)s0 * 64 + jb;
    int ecnt = s1 - s0;
    int e = 0;
    if (ecnt >= 4) {
      int sA = sp[0], sB = sp[1], sC = sp[2], sD = sp[3];
      while (e + 4 <= ecnt) {
        int4 kvA = *(const int4*)(qkvp + ((unsigned)(sA << 10) + (unsigned)kvoff));
        int4 kvB = *(const int4*)(qkvp + ((unsigned)(sB << 10) + (unsigned)kvoff));
        int4 kvC = *(const int4*)(qkvp + ((unsigned)(sC << 10) + (unsigned)kvoff));
        int4 kvD = *(const int4*)(qkvp + ((unsigned)(sD << 10) + (unsigned)kvoff));
        int2 tA = *(const int2*)(tep + (size_t)e * 64);
        int2 tB = *(const int2*)(tep + (size_t)(e + 1) * 64);
        int2 tC = *(const int2*)(tep + (size_t)(e + 2) * 64);
        int2 tD = *(const int2*)(tep + (size_t)(e + 3) * 64);
        int en = e + 4;
        if (en + 4 <= ecnt) {  // prefetch next quad's srcs (breaks src->kv chain)
          sA = sp[en]; sB = sp[en + 1]; sC = sp[en + 2]; sD = sp[en + 3];
        }
        edge_do(kvA, tA, q2, qsx, qsy, qsz, qsw, px, py, pz, pw, qb,
                denom, acc0, acc1, acc2, acc3);
        edge_do(kvB, tB, q2, qsx, qsy, qsz, qsw, px, py, pz, pw, qb,
                denom, acc0, acc1, acc2, acc3);
        edge_do(kvC, tC, q2, qsx, qsy, qsz, qsw, px, py, pz, pw, qb,
                denom, acc0, acc1, acc2, acc3);
        edge_do(kvD, tD, q2, qsx, qsy, qsz, qsw, px, py, pz, pw, qb,
                denom, acc0, acc1, acc2, acc3);
        e = en;
      }
    }
    for (; e < ecnt; ++e) {
      int s = sp[e];
      int4 kv = *(const int4*)(qkvp + ((unsigned)(s << 10) + (unsigned)kvoff));
      int2 t = *(const int2*)(tep + (size_t)e * 64);
      edge_do(kv, t, q2, qsx, qsy, qsz, qsw, px, py, pz, pw, qb,
              denom, acc0, acc1, acc2, acc3);
    }

    float inv = 1.f / (denom + 1e-16f);
    ushort4 r;
    r.x = f2bf(fmaxf(acc0 * inv, 0.f));
    r.y = f2bf(fmaxf(acc1 * inv, 0.f));
    r.z = f2bf(fmaxf(acc2 * inv, 0.f));
    r.w = f2bf(fmaxf(acc3 * inv, 0.f));
    *(ushort4*)(xout + (size_t)n * HC + c) = r;
    if (DOY) {
      float yv = bf2f(r.x) * wcv0 + bf2f(r.y) * wcv1 +
                 bf2f(r.z) * wcv2 + bf2f(r.w) * wcv3;
      yv = dpp_row_allsum(yv);
      yv += __shfl_xor(yv, 16);
      yv += __shfl_xor(yv, 32);
      if (lane == 0) ynode[n] = yv;
    }

    // rotate pipeline
    n = n1; pg = gnew;
    s0 = s0n; s1 = s1n; q2 = q2n; p2 = p2n;
  }
}

// ---------------- out[e] = y[src] + y[dst] + bc ----------------
__global__ __launch_bounds__(256) void final2_kernel(
    const int* __restrict__ flags, const void* __restrict__ eidx,
    const float* __restrict__ y, const void* __restrict__ bc,
    void* __restrict__ out) {
  bool is64 = flags[0] != 0, fbf = flags[1] != 0;
  int e = blockIdx.x * 256 + threadIdx.x;
  if (e >= NE) return;
  int src = ldsrc(eidx, e, is64);
  int dst = lddst(eidx, e, is64);
  if ((unsigned)src >= NN) src = 0;
  if ((unsigned)dst >= NN) dst = 0;
  stout(out, e, y[src] + y[dst] + ldf(bc, 0, fbf), fbf);
}

extern "C" void kernel_launch(void* const* d_in, const int* in_sizes, int n_in,
                              void* d_out, int out_size, void* d_ws, size_t ws_size,
                              hipStream_t stream) {
  const void* eidx  = d_in[0];
  const void* rawt  = d_in[1];
  const void* noise = d_in[2];
  const void* nemb  = d_in[3];
  const void *wq1 = d_in[4],  *bq1 = d_in[5];
  const void *wk1 = d_in[6],  *bk1 = d_in[7];
  const void *wv1 = d_in[8],  *bv1 = d_in[9];
  const void *wt1 = d_in[10], *bt1 = d_in[11];
  const void *wq2 = d_in[12], *bq2 = d_in[13];
  const void *wk2 = d_in[14], *bk2 = d_in[15];
  const void *wv2 = d_in[16], *bv2 = d_in[17];
  const void *wt2 = d_in[18], *bt2 = d_in[19];
  const void *wcp = d_in[20], *bcp = d_in[21];

  char* ws = (char*)d_ws;
  size_t off = 0;
  auto alloc = [&](size_t bytes) -> void* {
    void* p = ws + off;
    off += (bytes + 255) & ~(size_t)255;
    return p;
  };
  int*   flags  = (int*)alloc(256);
  float* divt   = (float*)alloc(256);
  u16*   WtBig  = (u16*)alloc((size_t)NB * HC * 2);
  float* biasBig= (float*)alloc((size_t)NB * 4);
  u16*   qkvp   = (u16*)alloc((size_t)NN * NB * 2);
  u16*   x1     = (u16*)alloc((size_t)NN * HC * 2);
  u16*   x2     = (u16*)alloc((size_t)NN * HC * 2);
  float* ynode  = (float*)alloc((size_t)NN * 4);
  int* offsets  = (int*)alloc((size_t)(NN + 1) * 4);
  int* cursor   = (int*)alloc((size_t)NN * 4);
  int* bsum     = (int*)alloc(256 * 4);
  int* ssrc     = (int*)alloc((size_t)NE * 4);
  float* stt    = (float*)alloc((size_t)NE * 4);
  u16* te_s     = (u16*)alloc((size_t)NE * 64 * 2);
  size_t need = off;

  int gN = (NN + 255) / 256, gE = (NE + 255) / 256;
  int nb = (NN + 255) / 256;

  if (ws_size < 1024) {
    raw_sentinel_kernel<<<gE, 256, 0, stream>>>((u16*)d_out);
    return;
  }
  devinit_kernel<<<1, 64, 0, stream>>>(eidx, nemb, flags, divt);
  if (need > ws_size) {
    sentinel_kernel<<<gE, 256, 0, stream>>>(flags, d_out);
    return;
  }

  // CSR by dst (+ sorted src / time)
  zero_kernel<<<gN, 256, 0, stream>>>(cursor, NN);
  hist_kernel<<<gE, 256, 0, stream>>>(flags, eidx, cursor);
  scan1_kernel<<<nb, 256, 0, stream>>>(cursor, offsets, bsum, NN);
  scan2_kernel<<<1, 256, 0, stream>>>(bsum, offsets, nb, NN);
  scan3_kernel<<<nb, 256, 0, stream>>>(offsets, bsum, cursor, NN);
  fill_kernel<<<gE, 256, 0, stream>>>(flags, eidx, rawt, noise, cursor, ssrc, stt);

  int gTe = (NE * 32 + 255) / 256;
  te_kernel<<<gTe, 256, 0, stream>>>(stt, divt, te_s);

  dim3 ggemm((NN + 127) / 128, NB / 128);   // 157 x 8
  dim3 gt1(NIN / 64, 4, 3), gt2(HC / 64, 4, 3);

  // ---- Layer 1 (A = raw node_emb, K=128) ----
  transw3_kernel<<<gt1, 256, 0, stream>>>(flags, wq1, wk1, wv1, WtBig, NIN);
  wcombbias_kernel<<<260, 256, 0, stream>>>(flags, wt1, WtBig, WtBig + (size_t)768 * NIN,
                                            bq1, bk1, bv1, biasBig, NIN);
  gemm_mfma<false><<<ggemm, 256, 0, stream>>>(flags, nemb, WtBig, biasBig, qkvp, NN, NIN);
  aggfused_kernel<0><<<AGG_BLOCKS, 256, 0, stream>>>(flags, ssrc, offsets, te_s, qkvp, bt1,
                                                     x1, wcp, ynode, flags + 2);

  // ---- Layer 2 (A = bf16 x1, K=256) ----
  transw3_kernel<<<gt2, 256, 0, stream>>>(flags, wq2, wk2, wv2, WtBig, HC);
  wcombbias_kernel<<<260, 256, 0, stream>>>(flags, wt2, WtBig, WtBig + (size_t)768 * HC,
                                            bq2, bk2, bv2, biasBig, HC);
  gemm_mfma<true><<<ggemm, 256, 0, stream>>>(flags, x1, WtBig, biasBig, qkvp, NN, HC);
  aggfused_kernel<1><<<AGG_BLOCKS, 256, 0, stream>>>(flags, ssrc, offsets, te_s, qkvp, bt2,
                                                     x2, wcp, ynode, flags + 3);

  // Edge scorer epilogue
  final2_kernel<<<gE, 256, 0, stream>>>(flags, eidx, ynode, bcp, d_out);
}

// Round 2
// 385.134 us; speedup vs baseline: 2.4832x; 2.4832x over previous
//
#include <hip/hip_runtime.h>
#include <hip/hip_fp16.h>
#include <math.h>

// Problem constants
#define NN   20000     // nodes
#define NE   320000    // edges
#define NIN  128       // node input dim
#define HC   256       // heads(4) * hidden(64)
#define NB   1024      // fused GEMM output width: [q | kv-interleaved | qproj]

// aggfused work distribution: 1250 blocks x 4 waves = 5000 waves,
// each wave handles exactly NN/5000 = 4 strided nodes (static, no atomics --
// round-1's single-address work-queue atomic serialized the whole kernel).
#define AGG_BLOCKS 1250
#define AGG_STRIDE 5000
#define LOG2E_8    0.18033688f   // log2(e)/8 -- folds the 1/sqrt(64) scale + exp->exp2

typedef unsigned short u16;
typedef __attribute__((ext_vector_type(8))) short bf16x8;
typedef __attribute__((ext_vector_type(8))) unsigned short u16x8;
typedef __attribute__((ext_vector_type(4))) float f32x4;

__device__ __forceinline__ float bf2f(u16 u) {
  union { unsigned int i; float f; } x;
  x.i = ((unsigned int)u) << 16;
  return x.f;
}
__device__ __forceinline__ u16 f2bf(float f) {
  union { float f; unsigned int i; } x;
  x.f = f;
  unsigned int r = x.i + 0x7fffu + ((x.i >> 16) & 1u);
  return (u16)(r >> 16);
}
// packed-pair bf16 unpack: lo = <<16, hi = mask (1 VALU op each)
__device__ __forceinline__ float bflo(int v) {
  union { int i; float f; } x; x.i = v << 16; return x.f;
}
__device__ __forceinline__ float bfhi(int v) {
  union { int i; float f; } x; x.i = v & 0xffff0000; return x.f;
}

// dtype-flexible loads (flags detected on device each launch)
__device__ __forceinline__ float ldf(const void* p, int i, bool fbf) {
  return fbf ? bf2f(((const u16*)p)[i]) : ((const float*)p)[i];
}
__device__ __forceinline__ int ldsrc(const void* p, int e, bool is64) {
  const int* p32 = (const int*)p;
  return is64 ? p32[2 * e] : p32[e];
}
__device__ __forceinline__ int lddst(const void* p, int e, bool is64) {
  const int* p32 = (const int*)p;
  return is64 ? p32[2 * (NE + e)] : p32[NE + e];
}
__device__ __forceinline__ void stout(void* p, int i, float v, bool fbf) {
  if (fbf) ((u16*)p)[i] = f2bf(v);
  else ((float*)p)[i] = v;
}

// async global->LDS, 16B per lane
__device__ __forceinline__ void gload_lds16(const u16* g, u16* l) {
  __builtin_amdgcn_global_load_lds(
      (const __attribute__((address_space(1))) void*)g,
      (__attribute__((address_space(3))) void*)l, 16, 0, 0);
}

// 16-lane (row) all-sum via DPP row_ror adds: pure VALU, replaces 4 ds_bpermute.
__device__ __forceinline__ float dpp_row_allsum(float s) {
  union fi { float f; int i; };
  fi a, b;
  a.f = s;
  b.i = __builtin_amdgcn_update_dpp(0, a.i, 0x121, 0xf, 0xf, true); a.f += b.f;
  b.i = __builtin_amdgcn_update_dpp(0, a.i, 0x122, 0xf, 0xf, true); a.f += b.f;
  b.i = __builtin_amdgcn_update_dpp(0, a.i, 0x124, 0xf, 0xf, true); a.f += b.f;
  b.i = __builtin_amdgcn_update_dpp(0, a.i, 0x128, 0xf, 0xf, true); a.f += b.f;
  return a.f;
}

__device__ __forceinline__ float fexp2(float x) {
#if __has_builtin(__builtin_amdgcn_exp2f)
  return __builtin_amdgcn_exp2f(x);
#else
  return exp2f(x);
#endif
}

#if __has_builtin(__builtin_amdgcn_fdot2_f32_bf16)
#define HAS_BF16_DOT2 1
typedef __attribute__((ext_vector_type(2))) __bf16 bfv2_t;
__device__ __forceinline__ float qkdot2(int a, int b, float c) {
  return __builtin_amdgcn_fdot2_f32_bf16(__builtin_bit_cast(bfv2_t, a),
                                         __builtin_bit_cast(bfv2_t, b), c, false);
}
#else
#define HAS_BF16_DOT2 0
#endif

// one edge: alpha partial -> row reduce -> exp2 -> accumulate (no max tracking;
// |alpha| <= ~3 by construction, f32 exp safe by a huge margin)
__device__ __forceinline__ void edge_do(int4 kv, int2 t, int2 q2,
    float qsx, float qsy, float qsz, float qsw,
    float px, float py, float pz, float pw, float qb,
    float& denom, float& a0, float& a1, float& a2, float& a3) {
  float2 f01 = __half22float2(__builtin_bit_cast(__half2, t.x));
  float2 f23 = __half22float2(__builtin_bit_cast(__half2, t.y));
  float stp = f01.x * px + f01.y * py + f23.x * pz + f23.y * pw;
#if HAS_BF16_DOT2
  float sqk = qkdot2(kv.y, q2.y, qkdot2(kv.x, q2.x, 0.f));
  float partial = sqk * LOG2E_8 + stp;
#else
  float partial = stp + qsx * bflo(kv.x) + qsy * bfhi(kv.x) +
                  qsz * bflo(kv.y) + qsw * bfhi(kv.y);
#endif
  float a = dpp_row_allsum(partial) + qb;
  float ea = fexp2(a);
  denom += ea;
  a0 = fmaf(ea, bflo(kv.z), a0);
  a1 = fmaf(ea, bfhi(kv.z), a1);
  a2 = fmaf(ea, bflo(kv.w), a2);
  a3 = fmaf(ea, bfhi(kv.w), a3);
}

// ---------------- detection + div_term init ----------------
__global__ void devinit_kernel(const void* __restrict__ eidx,
                               const void* __restrict__ nemb,
                               int* __restrict__ flags, float* __restrict__ divt) {
  int lane = threadIdx.x;
  if (lane < 32) {
    const float c32 = (float)(-0.14391156831212787);
    float prod = (float)(2 * lane) * c32;
    divt[lane] = (float)exp((double)prod);
  }
  if (lane == 0) {
    const int* p32 = (const int*)eidx;
    int is64 = 1;
    for (int i = 1; i < 128; i += 2)
      if (p32[i] != 0) { is64 = 0; break; }
    const u16* q16 = (const u16*)nemb;
    int fbf = 1;
    for (int i = 0; i < 128; i += 2) {
      unsigned e = (q16[i] >> 7) & 0xFF;
      if (e < 90 || e > 140) { fbf = 0; break; }
    }
    flags[0] = is64;
    flags[1] = fbf;
  }
}

__global__ void sentinel_kernel(const int* __restrict__ flags, void* __restrict__ out) {
  int i = blockIdx.x * 256 + threadIdx.x;
  if (i < NE) stout(out, i, 3000.0f, flags[1] != 0);
}
__global__ void raw_sentinel_kernel(u16* __restrict__ out) {
  int i = blockIdx.x * 256 + threadIdx.x;
  if (i < NE) out[i] = f2bf(3000.0f);
}

// ---------------- CSR build ----------------
__global__ void zero_kernel(int* __restrict__ p, int n) {
  int i = blockIdx.x * 256 + threadIdx.x;
  if (i < n) p[i] = 0;
}

__global__ void hist_kernel(const int* __restrict__ flags, const void* __restrict__ eidx,
                            int* __restrict__ cnt) {
  bool is64 = flags[0] != 0;
  int e = blockIdx.x * 256 + threadIdx.x;
  if (e < NE) {
    int d = lddst(eidx, e, is64);
    if ((unsigned)d < NN) atomicAdd(&cnt[d], 1);
  }
}

__global__ void scan1_kernel(const int* __restrict__ cnt, int* __restrict__ offs,
                             int* __restrict__ bsum, int n) {
  __shared__ int s[256];
  int b = blockIdx.x, t = threadIdx.x, i = b * 256 + t;
  int x = (i < n) ? cnt[i] : 0;
  s[t] = x;
  __syncthreads();
  for (int off = 1; off < 256; off <<= 1) {
    int y = (t >= off) ? s[t - off] : 0;
    __syncthreads();
    s[t] += y;
    __syncthreads();
  }
  if (i < n) offs[i] = s[t] - x;
  if (t == 255) bsum[b] = s[t];
}

__global__ void scan2_kernel(int* __restrict__ bsum, int* __restrict__ offs,
                             int nb, int n) {
  __shared__ int s[256];
  int t = threadIdx.x;
  int x = (t < nb) ? bsum[t] : 0;
  s[t] = x;
  __syncthreads();
  for (int off = 1; off < 256; off <<= 1) {
    int y = (t >= off) ? s[t - off] : 0;
    __syncthreads();
    s[t] += y;
    __syncthreads();
  }
  if (t < nb) bsum[t] = s[t] - x;
  if (t == 255) offs[n] = s[t];
}

__global__ void scan3_kernel(int* __restrict__ offs, const int* __restrict__ bsum,
                             int* __restrict__ cursor, int n) {
  int i = blockIdx.x * 256 + threadIdx.x;
  if (i < n) {
    int v = offs[i] + bsum[blockIdx.x];
    offs[i] = v;
    cursor[i] = v;
  }
}

__global__ void fill_kernel(const int* __restrict__ flags, const void* __restrict__ eidx,
                            const void* __restrict__ rawt, const void* __restrict__ noise,
                            int* __restrict__ cursor, int* __restrict__ ssrc,
                            float* __restrict__ stt) {
  bool is64 = flags[0] != 0, fbf = flags[1] != 0;
  int e = blockIdx.x * 256 + threadIdx.x;
  if (e < NE) {
    int d = lddst(eidx, e, is64);
    if ((unsigned)d < NN) {
      int pos = atomicAdd(&cursor[d], 1);
      if ((unsigned)pos < NE) {
        int src = ldsrc(eidx, e, is64);
        if ((unsigned)src >= NN) src = 0;
        ssrc[pos] = src;
        stt[pos] = ldf(rawt, e, fbf) + ldf(noise, e, fbf);
      }
    }
  }
}

// ---------------- te_s[p][64] (f16) — double range reduction + HW sin/cos --------
__global__ __launch_bounds__(256) void te_kernel(
    const float* __restrict__ stt, const float* __restrict__ divt,
    u16* __restrict__ te_s) {
  int idx = blockIdx.x * 256 + threadIdx.x;
  int p = idx >> 5;          // 32 freqs per edge
  if (p >= NE) return;
  int f = idx & 31;
  float tt = stt[p];
  float arg = tt * divt[f];
  double rev = (double)arg * 0.15915494309189535;   // /(2π)
  double fr = rev - floor(rev);                     // [0,1) revolutions
  float frf = (float)fr;
  float sv = __builtin_amdgcn_sinf(frf);            // sin(2π·frf)
  float cv = __builtin_amdgcn_cosf(frf);            // cos(2π·frf)
  __half hs = __float2half(sv), hc = __float2half(cv);
  unsigned int packed = (unsigned int)(*(u16*)&hs) | ((unsigned int)(*(u16*)&hc) << 16);
  ((unsigned int*)te_s)[(size_t)p * 32 + f] = packed;
}

// ---------------- merged weight transpose: 3 matrices -> WtBig rows 0/256/512 -----
__global__ void transw3_kernel(const int* __restrict__ flags, const void* __restrict__ W0,
                               const void* __restrict__ W1, const void* __restrict__ W2,
                               u16* __restrict__ WtBig, int K) {
  bool fbf = flags[1] != 0;
  __shared__ u16 tile[64][65];
  int z = blockIdx.z;
  const void* W = (z == 0) ? W0 : (z == 1) ? W1 : W2;
  u16* dst = WtBig + (size_t)z * 256 * K;
  int kb = blockIdx.x * 64, cb = blockIdx.y * 64;
  int tx = threadIdx.x & 63, ty = threadIdx.x >> 6;
  for (int i = ty; i < 64; i += 4)
    tile[tx][i] = f2bf(ldf(W, (kb + i) * HC + cb + tx, fbf));
  __syncthreads();
  for (int i = ty; i < 64; i += 4)
    dst[(size_t)(cb + i) * K + kb + tx] = tile[i][tx];
}

// ---------------- wcomb + biasBig merged ----------------
__global__ void wcombbias_kernel(const int* __restrict__ flags, const void* __restrict__ wt,
                                 const u16* __restrict__ Wqt, u16* __restrict__ Wout,
                                 const void* __restrict__ bq, const void* __restrict__ bk,
                                 const void* __restrict__ bv, float* __restrict__ biasBig,
                                 int K) {
  bool fbf = flags[1] != 0;
  int b = blockIdx.x, t = threadIdx.x;
  if (b < 256) {
    __shared__ float wrow[64];
    int j = b, h = j >> 6;
    if (t < 64) wrow[t] = ldf(wt, (j & 63) * HC + h * 64 + t, fbf);
    __syncthreads();
    if (t < K) {
      float s = 0.f;
#pragma unroll 8
      for (int mm = 0; mm < 64; ++mm)
        s += wrow[mm] * bf2f(Wqt[(size_t)(h * 64 + mm) * K + t]);
      Wout[(size_t)j * K + t] = f2bf(s);
    }
  } else if (b < 259) {
    int bb = b - 256;
    const void* p = (bb == 0) ? bq : (bb == 1) ? bk : bv;
    biasBig[bb * 256 + t] = ldf(p, t, fbf);
  } else {
    int j = t, h = j >> 6;
    float s = 0.f;
    for (int mm = 0; mm < 64; ++mm)
      s += ldf(bq, h * 64 + mm, fbf) * ldf(wt, (j & 63) * HC + h * 64 + mm, fbf);
    biasBig[768 + j] = s;
  }
}

// ---------------- fused MFMA GEMM — 128x128 tile (m97-style) ----------------------
template <bool AWS>
__global__ __launch_bounds__(256) void gemm_mfma(
    const int* __restrict__ flags, const void* __restrict__ Ap,
    const u16* __restrict__ Wt, const float* __restrict__ bias,
    u16* __restrict__ C, int M, int K) {
  bool fbf = flags[1] != 0;
  __shared__ u16 As[128 * 32];
  __shared__ u16 Bs[128 * 32];
  int tid = threadIdx.x;
  int rb = blockIdx.x * 128, cb = blockIdx.y * 128;
  int wave = tid >> 6, lane = tid & 63;
  int l15 = lane & 15, quad = lane >> 4;
  int mbase = (wave >> 1) * 64, nbase = (wave & 1) * 64;

  f32x4 acc[4][4];
#pragma unroll
  for (int mt = 0; mt < 4; ++mt)
#pragma unroll
    for (int nt = 0; nt < 4; ++nt)
#pragma unroll
      for (int r = 0; r < 4; ++r) acc[mt][nt][r] = 0.f;

  int srow0 = tid >> 2, schunk0 = tid & 3;
  int srow1 = (tid + 256) >> 2, schunk1 = (tid + 256) & 3;
  int gchunk0 = schunk0 ^ (srow0 & 3);
  int gchunk1 = schunk1 ^ (srow1 & 3);
  int arow0 = rb + srow0; if (arow0 >= M) arow0 = M - 1;
  int arow1 = rb + srow1; if (arow1 >= M) arow1 = M - 1;
  u16* asl0 = &As[srow0 * 32 + schunk0 * 8];
  u16* asl1 = &As[srow1 * 32 + schunk1 * 8];
  u16* bsl0 = &Bs[srow0 * 32 + schunk0 * 8];
  u16* bsl1 = &Bs[srow1 * 32 + schunk1 * 8];
  const u16* bsrc0 = Wt + (size_t)(cb + srow0) * K + gchunk0 * 8;
  const u16* bsrc1 = Wt + (size_t)(cb + srow1) * K + gchunk1 * 8;
  const bool adirect = AWS || fbf;
  const u16* asrc0 = adirect ? ((const u16*)Ap + (size_t)arow0 * K + gchunk0 * 8) : (const u16*)0;
  const u16* asrc1 = adirect ? ((const u16*)Ap + (size_t)arow1 * K + gchunk1 * 8) : (const u16*)0;

  for (int kk = 0; kk < K; kk += 32) {
    if (adirect) {
      gload_lds16(asrc0 + kk, asl0);
      gload_lds16(asrc1 + kk, asl1);
    } else {
      const float* A0 = (const float*)Ap + (size_t)arow0 * K + kk + gchunk0 * 8;
      const float* A1 = (const float*)Ap + (size_t)arow1 * K + kk + gchunk1 * 8;
      bf16x8 t0, t1;
#pragma unroll
      for (int i = 0; i < 8; ++i) { t0[i] = (short)f2bf(A0[i]); t1[i] = (short)f2bf(A1[i]); }
      *(bf16x8*)asl0 = t0;
      *(bf16x8*)asl1 = t1;
    }
    gload_lds16(bsrc0 + kk, bsl0);
    gload_lds16(bsrc1 + kk, bsl1);
    __syncthreads();

    bf16x8 bfrag[4];
#pragma unroll
    for (int nt = 0; nt < 4; ++nt) {
      int col = nbase + nt * 16 + l15;
      bfrag[nt] = *(const bf16x8*)&Bs[col * 32 + ((quad ^ (col & 3)) * 8)];
    }
#pragma unroll
    for (int mt = 0; mt < 4; ++mt) {
      int row = mbase + mt * 16 + l15;
      bf16x8 afrag = *(const bf16x8*)&As[row * 32 + ((quad ^ (row & 3)) * 8)];
#pragma unroll
      for (int nt = 0; nt < 4; ++nt)
        acc[mt][nt] = __builtin_amdgcn_mfma_f32_16x16x32_bf16(afrag, bfrag[nt], acc[mt][nt], 0, 0, 0);
    }
    __syncthreads();
  }

#pragma unroll
  for (int nt = 0; nt < 4; ++nt) {
    int gcol = cb + nbase + nt * 16 + l15;
    float bv = bias[gcol];
    int scol;
    if (gcol < 256) scol = gcol;
    else if (gcol < 512) { int cc = gcol - 256; scol = 256 + ((cc >> 2) << 3) + (cc & 3); }
    else if (gcol < 768) { int cc = gcol - 512; scol = 256 + ((cc >> 2) << 3) + 4 + (cc & 3); }
    else scol = gcol;
#pragma unroll
    for (int mt = 0; mt < 4; ++mt) {
#pragma unroll
      for (int r = 0; r < 4; ++r) {
        int grow = rb + mbase + mt * 16 + quad * 4 + r;
        if (grow < M) C[(size_t)grow * NB + scol] = f2bf(acc[mt][nt][r] + bv);
      }
    }
  }
}

// ---------------- fused alpha + softmax + aggregation + relu -----------------------
// v3: static strided 4-nodes-per-wave (no atomics; round-1's single-address
// work-queue serialized everything), 1-ahead static prefetch pipeline, DPP
// row-rotate reduce, no max tracking (direct exp2, scales folded), packed
// bf16 unpack, optional bf16 dot2.
template <int DOY>
__global__ __launch_bounds__(256) void aggfused_kernel(
    const int* __restrict__ flags, const int* __restrict__ ssrc,
    const int* __restrict__ offsets, const u16* __restrict__ te_s,
    const u16* __restrict__ qkvp, const void* __restrict__ bt,
    u16* __restrict__ xout, const void* __restrict__ wc,
    float* __restrict__ ynode) {
  bool fbf = flags[1] != 0;
  int lane = threadIdx.x & 63;
  int c = lane * 4;
  int jb = c & 63;
  int kvoff = 256 + lane * 8;

  // node-invariant per-lane data
  float btv0 = ldf(bt, c + 0, fbf), btv1 = ldf(bt, c + 1, fbf);
  float btv2 = ldf(bt, c + 2, fbf), btv3 = ldf(bt, c + 3, fbf);
  float wcv0 = 0.f, wcv1 = 0.f, wcv2 = 0.f, wcv3 = 0.f;
  if (DOY) {
    wcv0 = ldf(wc, c + 0, fbf); wcv1 = ldf(wc, c + 1, fbf);
    wcv2 = ldf(wc, c + 2, fbf); wcv3 = ldf(wc, c + 3, fbf);
  }

  // first node of this wave; prefetch its data
  int n = blockIdx.x * 4 + (threadIdx.x >> 6);   // 0..4999
  int s0 = offsets[n], s1 = offsets[n + 1];
  int2 q2 = *(const int2*)(qkvp + (size_t)n * NB + c);
  int2 p2 = *(const int2*)(qkvp + (size_t)n * NB + 768 + c);

  while (n < NN) {
    // next node is statically known: issue its loads now, consume next iter
    int n1 = n + AGG_STRIDE;
    int n1c = (n1 < NN) ? n1 : 0;
    int s0n = offsets[n1c], s1n = offsets[n1c + 1];
    int2 q2n = *(const int2*)(qkvp + (size_t)n1c * NB + c);
    int2 p2n = *(const int2*)(qkvp + (size_t)n1c * NB + 768 + c);

    // ---- process node n (data already resident) ----
    float qx = bflo(q2.x), qy = bfhi(q2.x), qz = bflo(q2.y), qw = bfhi(q2.y);
    float px = bflo(p2.x) * LOG2E_8, py = bfhi(p2.x) * LOG2E_8;
    float pz = bflo(p2.y) * LOG2E_8, pw = bfhi(p2.y) * LOG2E_8;
    float pb = qx * btv0 + qy * btv1 + qz * btv2 + qw * btv3;
    float qb = dpp_row_allsum(pb) * LOG2E_8;
    float qsx = qx * LOG2E_8, qsy = qy * LOG2E_8;
    float qsz = qz * LOG2E_8, qsw = qw * LOG2E_8;

    float denom = 0.f, acc0 = 0.f, acc1 = 0.f, acc2 = 0.f, acc3 = 0.f;
    const int* sp = ssrc + s0;
    const u16* tep = te_s + (size_t)s0 * 64 + jb;
    int ecnt = s1 - s0;
    int e = 0;
    if (ecnt >= 4) {
      int sA = sp[0], sB = sp[1], sC = sp[2], sD = sp[3];
      while (e + 4 <= ecnt) {
        int4 kvA = *(const int4*)(qkvp + ((unsigned)(sA << 10) + (unsigned)kvoff));
        int4 kvB = *(const int4*)(qkvp + ((unsigned)(sB << 10) + (unsigned)kvoff));
        int4 kvC = *(const int4*)(qkvp + ((unsigned)(sC << 10) + (unsigned)kvoff));
        int4 kvD = *(const int4*)(qkvp + ((unsigned)(sD << 10) + (unsigned)kvoff));
        int2 tA = *(const int2*)(tep + (size_t)e * 64);
        int2 tB = *(const int2*)(tep + (size_t)(e + 1) * 64);
        int2 tC = *(const int2*)(tep + (size_t)(e + 2) * 64);
        int2 tD = *(const int2*)(tep + (size_t)(e + 3) * 64);
        int en = e + 4;
        if (en + 4 <= ecnt) {  // prefetch next quad's srcs (breaks src->kv chain)
          sA = sp[en]; sB = sp[en + 1]; sC = sp[en + 2]; sD = sp[en + 3];
        }
        edge_do(kvA, tA, q2, qsx, qsy, qsz, qsw, px, py, pz, pw, qb,
                denom, acc0, acc1, acc2, acc3);
        edge_do(kvB, tB, q2, qsx, qsy, qsz, qsw, px, py, pz, pw, qb,
                denom, acc0, acc1, acc2, acc3);
        edge_do(kvC, tC, q2, qsx, qsy, qsz, qsw, px, py, pz, pw, qb,
                denom, acc0, acc1, acc2, acc3);
        edge_do(kvD, tD, q2, qsx, qsy, qsz, qsw, px, py, pz, pw, qb,
                denom, acc0, acc1, acc2, acc3);
        e = en;
      }
    }
    for (; e < ecnt; ++e) {
      int s = sp[e];
      int4 kv = *(const int4*)(qkvp + ((unsigned)(s << 10) + (unsigned)kvoff));
      int2 t = *(const int2*)(tep + (size_t)e * 64);
      edge_do(kv, t, q2, qsx, qsy, qsz, qsw, px, py, pz, pw, qb,
              denom, acc0, acc1, acc2, acc3);
    }

    float inv = 1.f / (denom + 1e-16f);
    ushort4 r;
    r.x = f2bf(fmaxf(acc0 * inv, 0.f));
    r.y = f2bf(fmaxf(acc1 * inv, 0.f));
    r.z = f2bf(fmaxf(acc2 * inv, 0.f));
    r.w = f2bf(fmaxf(acc3 * inv, 0.f));
    *(ushort4*)(xout + (size_t)n * HC + c) = r;
    if (DOY) {
      float yv = bf2f(r.x) * wcv0 + bf2f(r.y) * wcv1 +
                 bf2f(r.z) * wcv2 + bf2f(r.w) * wcv3;
      yv = dpp_row_allsum(yv);
      yv += __shfl_xor(yv, 16);
      yv += __shfl_xor(yv, 32);
      if (lane == 0) ynode[n] = yv;
    }

    // rotate pipeline
    n = n1;
    s0 = s0n; s1 = s1n; q2 = q2n; p2 = p2n;
  }
}

// ---------------- out[e] = y[src] + y[dst] + bc ----------------
__global__ __launch_bounds__(256) void final2_kernel(
    const int* __restrict__ flags, const void* __restrict__ eidx,
    const float* __restrict__ y, const void* __restrict__ bc,
    void* __restrict__ out) {
  bool is64 = flags[0] != 0, fbf = flags[1] != 0;
  int e = blockIdx.x * 256 + threadIdx.x;
  if (e >= NE) return;
  int src = ldsrc(eidx, e, is64);
  int dst = lddst(eidx, e, is64);
  if ((unsigned)src >= NN) src = 0;
  if ((unsigned)dst >= NN) dst = 0;
  stout(out, e, y[src] + y[dst] + ldf(bc, 0, fbf), fbf);
}

extern "C" void kernel_launch(void* const* d_in, const int* in_sizes, int n_in,
                              void* d_out, int out_size, void* d_ws, size_t ws_size,
                              hipStream_t stream) {
  const void* eidx  = d_in[0];
  const void* rawt  = d_in[1];
  const void* noise = d_in[2];
  const void* nemb  = d_in[3];
  const void *wq1 = d_in[4],  *bq1 = d_in[5];
  const void *wk1 = d_in[6],  *bk1 = d_in[7];
  const void *wv1 = d_in[8],  *bv1 = d_in[9];
  const void *wt1 = d_in[10], *bt1 = d_in[11];
  const void *wq2 = d_in[12], *bq2 = d_in[13];
  const void *wk2 = d_in[14], *bk2 = d_in[15];
  const void *wv2 = d_in[16], *bv2 = d_in[17];
  const void *wt2 = d_in[18], *bt2 = d_in[19];
  const void *wcp = d_in[20], *bcp = d_in[21];

  char* ws = (char*)d_ws;
  size_t off = 0;
  auto alloc = [&](size_t bytes) -> void* {
    void* p = ws + off;
    off += (bytes + 255) & ~(size_t)255;
    return p;
  };
  int*   flags  = (int*)alloc(256);
  float* divt   = (float*)alloc(256);
  u16*   WtBig  = (u16*)alloc((size_t)NB * HC * 2);
  float* biasBig= (float*)alloc((size_t)NB * 4);
  u16*   qkvp   = (u16*)alloc((size_t)NN * NB * 2);
  u16*   x1     = (u16*)alloc((size_t)NN * HC * 2);
  u16*   x2     = (u16*)alloc((size_t)NN * HC * 2);
  float* ynode  = (float*)alloc((size_t)NN * 4);
  int* offsets  = (int*)alloc((size_t)(NN + 1) * 4);
  int* cursor   = (int*)alloc((size_t)NN * 4);
  int* bsum     = (int*)alloc(256 * 4);
  int* ssrc     = (int*)alloc((size_t)NE * 4);
  float* stt    = (float*)alloc((size_t)NE * 4);
  u16* te_s     = (u16*)alloc((size_t)NE * 64 * 2);
  size_t need = off;

  int gN = (NN + 255) / 256, gE = (NE + 255) / 256;
  int nb = (NN + 255) / 256;

  if (ws_size < 1024) {
    raw_sentinel_kernel<<<gE, 256, 0, stream>>>((u16*)d_out);
    return;
  }
  devinit_kernel<<<1, 64, 0, stream>>>(eidx, nemb, flags, divt);
  if (need > ws_size) {
    sentinel_kernel<<<gE, 256, 0, stream>>>(flags, d_out);
    return;
  }

  // CSR by dst (+ sorted src / time)
  zero_kernel<<<gN, 256, 0, stream>>>(cursor, NN);
  hist_kernel<<<gE, 256, 0, stream>>>(flags, eidx, cursor);
  scan1_kernel<<<nb, 256, 0, stream>>>(cursor, offsets, bsum, NN);
  scan2_kernel<<<1, 256, 0, stream>>>(bsum, offsets, nb, NN);
  scan3_kernel<<<nb, 256, 0, stream>>>(offsets, bsum, cursor, NN);
  fill_kernel<<<gE, 256, 0, stream>>>(flags, eidx, rawt, noise, cursor, ssrc, stt);

  int gTe = (NE * 32 + 255) / 256;
  te_kernel<<<gTe, 256, 0, stream>>>(stt, divt, te_s);

  dim3 ggemm((NN + 127) / 128, NB / 128);   // 157 x 8
  dim3 gt1(NIN / 64, 4, 3), gt2(HC / 64, 4, 3);

  // ---- Layer 1 (A = raw node_emb, K=128) ----
  transw3_kernel<<<gt1, 256, 0, stream>>>(flags, wq1, wk1, wv1, WtBig, NIN);
  wcombbias_kernel<<<260, 256, 0, stream>>>(flags, wt1, WtBig, WtBig + (size_t)768 * NIN,
                                            bq1, bk1, bv1, biasBig, NIN);
  gemm_mfma<false><<<ggemm, 256, 0, stream>>>(flags, nemb, WtBig, biasBig, qkvp, NN, NIN);
  aggfused_kernel<0><<<AGG_BLOCKS, 256, 0, stream>>>(flags, ssrc, offsets, te_s, qkvp, bt1,
                                                     x1, wcp, ynode);

  // ---- Layer 2 (A = bf16 x1, K=256) ----
  transw3_kernel<<<gt2, 256, 0, stream>>>(flags, wq2, wk2, wv2, WtBig, HC);
  wcombbias_kernel<<<260, 256, 0, stream>>>(flags, wt2, WtBig, WtBig + (size_t)768 * HC,
                                            bq2, bk2, bv2, biasBig, HC);
  gemm_mfma<true><<<ggemm, 256, 0, stream>>>(flags, x1, WtBig, biasBig, qkvp, NN, HC);
  aggfused_kernel<1><<<AGG_BLOCKS, 256, 0, stream>>>(flags, ssrc, offsets, te_s, qkvp, bt2,
                                                     x2, wcp, ynode);

  // Edge scorer epilogue
  final2_kernel<<<gE, 256, 0, stream>>>(flags, eidx, ynode, bcp, d_out);
}

// Round 3
// 358.977 us; speedup vs baseline: 2.6641x; 1.0729x over previous
//
#include <hip/hip_runtime.h>
#include <hip/hip_fp16.h>
#include <math.h>

// Problem constants
#define NN   20000     // nodes
#define NE   320000    // edges
#define NIN  128       // node input dim
#define HC   256       // heads(4) * hidden(64)
#define NB   1024      // fused GEMM output width: [q | kv-interleaved | qproj]

// aggfused work distribution: 2500 blocks x 4 waves = 10000 waves, 2 strided
// nodes each. 44-VGPR kernel -> 32 waves/CU residency cap; 10000 waves gives
// ~8 resident blocks/CU (round-2's 5000 waves could only reach ~20/CU).
#define AGG_BLOCKS 2500
#define AGG_STRIDE 10000
#define LOG2E_8    0.18033688f   // log2(e)/8 -- folds the 1/sqrt(64) scale + exp->exp2

typedef unsigned short u16;
typedef __attribute__((ext_vector_type(8))) short bf16x8;
typedef __attribute__((ext_vector_type(4))) float f32x4;

__device__ __forceinline__ float bf2f(u16 u) {
  union { unsigned int i; float f; } x;
  x.i = ((unsigned int)u) << 16;
  return x.f;
}
__device__ __forceinline__ u16 f2bf(float f) {
  union { float f; unsigned int i; } x;
  x.f = f;
  unsigned int r = x.i + 0x7fffu + ((x.i >> 16) & 1u);
  return (u16)(r >> 16);
}
// packed-pair bf16 unpack: lo = <<16, hi = mask (1 VALU op each)
__device__ __forceinline__ float bflo(int v) {
  union { int i; float f; } x; x.i = v << 16; return x.f;
}
__device__ __forceinline__ float bfhi(int v) {
  union { int i; float f; } x; x.i = v & 0xffff0000; return x.f;
}

// dtype-flexible loads (flags detected on device each launch)
__device__ __forceinline__ float ldf(const void* p, int i, bool fbf) {
  return fbf ? bf2f(((const u16*)p)[i]) : ((const float*)p)[i];
}
__device__ __forceinline__ int ldsrc(const void* p, int e, bool is64) {
  const int* p32 = (const int*)p;
  return is64 ? p32[2 * e] : p32[e];
}
__device__ __forceinline__ int lddst(const void* p, int e, bool is64) {
  const int* p32 = (const int*)p;
  return is64 ? p32[2 * (NE + e)] : p32[NE + e];
}
__device__ __forceinline__ void stout(void* p, int i, float v, bool fbf) {
  if (fbf) ((u16*)p)[i] = f2bf(v);
  else ((float*)p)[i] = v;
}

// async global->LDS, 16B per lane
__device__ __forceinline__ void gload_lds16(const u16* g, u16* l) {
  __builtin_amdgcn_global_load_lds(
      (const __attribute__((address_space(1))) void*)g,
      (__attribute__((address_space(3))) void*)l, 16, 0, 0);
}

// 16-lane (row) all-sum via DPP row_ror adds: pure VALU, replaces 4 ds_bpermute.
__device__ __forceinline__ float dpp_row_allsum(float s) {
  union fi { float f; int i; };
  fi a, b;
  a.f = s;
  b.i = __builtin_amdgcn_update_dpp(0, a.i, 0x121, 0xf, 0xf, true); a.f += b.f;
  b.i = __builtin_amdgcn_update_dpp(0, a.i, 0x122, 0xf, 0xf, true); a.f += b.f;
  b.i = __builtin_amdgcn_update_dpp(0, a.i, 0x124, 0xf, 0xf, true); a.f += b.f;
  b.i = __builtin_amdgcn_update_dpp(0, a.i, 0x128, 0xf, 0xf, true); a.f += b.f;
  return a.f;
}

__device__ __forceinline__ float fexp2(float x) {
#if __has_builtin(__builtin_amdgcn_exp2f)
  return __builtin_amdgcn_exp2f(x);
#else
  return exp2f(x);
#endif
}

#if __has_builtin(__builtin_amdgcn_fdot2_f32_bf16)
#define HAS_BF16_DOT2 1
typedef __attribute__((ext_vector_type(2))) __bf16 bfv2_t;
__device__ __forceinline__ float qkdot2(int a, int b, float c) {
  return __builtin_amdgcn_fdot2_f32_bf16(__builtin_bit_cast(bfv2_t, a),
                                         __builtin_bit_cast(bfv2_t, b), c, false);
}
#else
#define HAS_BF16_DOT2 0
#endif

// one edge: inline time-encode (exact f32 Cody-Waite 1/2pi reduction of the
// f32 product arg = fl(tt*divt), matching the reference's sin(f32 arg)), then
// alpha partial -> DPP row reduce -> exp2 -> accumulate. No max tracking
// (|alpha| <= ~3 by construction, f32 exp2 safe by a huge margin).
__device__ __forceinline__ void edge_do(int4 kv, float tt, int2 q2,
    float dc0, float dc1,
    float qsx, float qsy, float qsz, float qsw,
    float px, float py, float pz, float pw, float qb,
    float& denom, float& a0, float& a1, float& a2, float& a3) {
  const float CH = 0.15915494f;                                    // f32(1/2pi)
  const float CL = (float)(0.15915494309189535 - (double)0.15915494f);
  float x0 = tt * dc0, x1 = tt * dc1;     // = reference's f32 arg
  float p0 = x0 * CH, p1 = x1 * CH;
  float e0 = fmaf(x0, CH, -p0), e1 = fmaf(x1, CH, -p1);
  e0 = fmaf(x0, CL, e0);  e1 = fmaf(x1, CL, e1);
  float fr0 = (p0 - rintf(p0)) + e0;      // revolutions, |fr| <= ~0.5
  float fr1 = (p1 - rintf(p1)) + e1;
  float sv0 = __builtin_amdgcn_sinf(fr0), cv0 = __builtin_amdgcn_cosf(fr0);
  float sv1 = __builtin_amdgcn_sinf(fr1), cv1 = __builtin_amdgcn_cosf(fr1);
  float stp = sv0 * px + cv0 * py + sv1 * pz + cv1 * pw;
#if HAS_BF16_DOT2
  float sqk = qkdot2(kv.y, q2.y, qkdot2(kv.x, q2.x, 0.f));
  float partial = sqk * LOG2E_8 + stp;
#else
  float partial = stp + qsx * bflo(kv.x) + qsy * bfhi(kv.x) +
                  qsz * bflo(kv.y) + qsw * bfhi(kv.y);
#endif
  float a = dpp_row_allsum(partial) + qb;
  float ea = fexp2(a);
  denom += ea;
  a0 = fmaf(ea, bflo(kv.z), a0);
  a1 = fmaf(ea, bfhi(kv.z), a1);
  a2 = fmaf(ea, bflo(kv.w), a2);
  a3 = fmaf(ea, bfhi(kv.w), a3);
}

// ---------------- detection + div_term init ----------------
__global__ void devinit_kernel(const void* __restrict__ eidx,
                               const void* __restrict__ nemb,
                               int* __restrict__ flags, float* __restrict__ divt) {
  int lane = threadIdx.x;
  if (lane < 32) {
    const float c32 = (float)(-0.14391156831212787);
    float prod = (float)(2 * lane) * c32;
    divt[lane] = (float)exp((double)prod);
  }
  if (lane == 0) {
    const int* p32 = (const int*)eidx;
    int is64 = 1;
    for (int i = 1; i < 128; i += 2)
      if (p32[i] != 0) { is64 = 0; break; }
    const u16* q16 = (const u16*)nemb;
    int fbf = 1;
    for (int i = 0; i < 128; i += 2) {
      unsigned e = (q16[i] >> 7) & 0xFF;
      if (e < 90 || e > 140) { fbf = 0; break; }
    }
    flags[0] = is64;
    flags[1] = fbf;
  }
}

__global__ void sentinel_kernel(const int* __restrict__ flags, void* __restrict__ out) {
  int i = blockIdx.x * 256 + threadIdx.x;
  if (i < NE) stout(out, i, 3000.0f, flags[1] != 0);
}
__global__ void raw_sentinel_kernel(u16* __restrict__ out) {
  int i = blockIdx.x * 256 + threadIdx.x;
  if (i < NE) out[i] = f2bf(3000.0f);
}

// ---------------- CSR build ----------------
__global__ void zero_kernel(int* __restrict__ p, int n) {
  int i = blockIdx.x * 256 + threadIdx.x;
  if (i < n) p[i] = 0;
}

__global__ void hist_kernel(const int* __restrict__ flags, const void* __restrict__ eidx,
                            int* __restrict__ cnt) {
  bool is64 = flags[0] != 0;
  int e = blockIdx.x * 256 + threadIdx.x;
  if (e < NE) {
    int d = lddst(eidx, e, is64);
    if ((unsigned)d < NN) atomicAdd(&cnt[d], 1);
  }
}

__global__ void scan1_kernel(const int* __restrict__ cnt, int* __restrict__ offs,
                             int* __restrict__ bsum, int n) {
  __shared__ int s[256];
  int b = blockIdx.x, t = threadIdx.x, i = b * 256 + t;
  int x = (i < n) ? cnt[i] : 0;
  s[t] = x;
  __syncthreads();
  for (int off = 1; off < 256; off <<= 1) {
    int y = (t >= off) ? s[t - off] : 0;
    __syncthreads();
    s[t] += y;
    __syncthreads();
  }
  if (i < n) offs[i] = s[t] - x;
  if (t == 255) bsum[b] = s[t];
}

__global__ void scan2_kernel(int* __restrict__ bsum, int* __restrict__ offs,
                             int nb, int n) {
  __shared__ int s[256];
  int t = threadIdx.x;
  int x = (t < nb) ? bsum[t] : 0;
  s[t] = x;
  __syncthreads();
  for (int off = 1; off < 256; off <<= 1) {
    int y = (t >= off) ? s[t - off] : 0;
    __syncthreads();
    s[t] += y;
    __syncthreads();
  }
  if (t < nb) bsum[t] = s[t] - x;
  if (t == 255) offs[n] = s[t];
}

__global__ void scan3_kernel(int* __restrict__ offs, const int* __restrict__ bsum,
                             int* __restrict__ cursor, int n) {
  int i = blockIdx.x * 256 + threadIdx.x;
  if (i < n) {
    int v = offs[i] + bsum[blockIdx.x];
    offs[i] = v;
    cursor[i] = v;
  }
}

__global__ void fill_kernel(const int* __restrict__ flags, const void* __restrict__ eidx,
                            const void* __restrict__ rawt, const void* __restrict__ noise,
                            int* __restrict__ cursor, int* __restrict__ ssrc,
                            float* __restrict__ stt) {
  bool is64 = flags[0] != 0, fbf = flags[1] != 0;
  int e = blockIdx.x * 256 + threadIdx.x;
  if (e < NE) {
    int d = lddst(eidx, e, is64);
    if ((unsigned)d < NN) {
      int pos = atomicAdd(&cursor[d], 1);
      if ((unsigned)pos < NE) {
        int src = ldsrc(eidx, e, is64);
        if ((unsigned)src >= NN) src = 0;
        ssrc[pos] = src;
        stt[pos] = ldf(rawt, e, fbf) + ldf(noise, e, fbf);
      }
    }
  }
}

// ---------------- merged weight transpose: 3 matrices -> WtBig rows 0/256/512 -----
__global__ void transw3_kernel(const int* __restrict__ flags, const void* __restrict__ W0,
                               const void* __restrict__ W1, const void* __restrict__ W2,
                               u16* __restrict__ WtBig, int K) {
  bool fbf = flags[1] != 0;
  __shared__ u16 tile[64][65];
  int z = blockIdx.z;
  const void* W = (z == 0) ? W0 : (z == 1) ? W1 : W2;
  u16* dst = WtBig + (size_t)z * 256 * K;
  int kb = blockIdx.x * 64, cb = blockIdx.y * 64;
  int tx = threadIdx.x & 63, ty = threadIdx.x >> 6;
  for (int i = ty; i < 64; i += 4)
    tile[tx][i] = f2bf(ldf(W, (kb + i) * HC + cb + tx, fbf));
  __syncthreads();
  for (int i = ty; i < 64; i += 4)
    dst[(size_t)(cb + i) * K + kb + tx] = tile[i][tx];
}

// ---------------- wcomb + biasBig merged ----------------
__global__ void wcombbias_kernel(const int* __restrict__ flags, const void* __restrict__ wt,
                                 const u16* __restrict__ Wqt, u16* __restrict__ Wout,
                                 const void* __restrict__ bq, const void* __restrict__ bk,
                                 const void* __restrict__ bv, float* __restrict__ biasBig,
                                 int K) {
  bool fbf = flags[1] != 0;
  int b = blockIdx.x, t = threadIdx.x;
  if (b < 256) {
    __shared__ float wrow[64];
    int j = b, h = j >> 6;
    if (t < 64) wrow[t] = ldf(wt, (j & 63) * HC + h * 64 + t, fbf);
    __syncthreads();
    if (t < K) {
      float s = 0.f;
#pragma unroll 8
      for (int mm = 0; mm < 64; ++mm)
        s += wrow[mm] * bf2f(Wqt[(size_t)(h * 64 + mm) * K + t]);
      Wout[(size_t)j * K + t] = f2bf(s);
    }
  } else if (b < 259) {
    int bb = b - 256;
    const void* p = (bb == 0) ? bq : (bb == 1) ? bk : bv;
    biasBig[bb * 256 + t] = ldf(p, t, fbf);
  } else {
    int j = t, h = j >> 6;
    float s = 0.f;
    for (int mm = 0; mm < 64; ++mm)
      s += ldf(bq, h * 64 + mm, fbf) * ldf(wt, (j & 63) * HC + h * 64 + mm, fbf);
    biasBig[768 + j] = s;
  }
}

// ---------------- fused MFMA GEMM — 128x128 tile (m97-style) ----------------------
template <bool AWS>
__global__ __launch_bounds__(256) void gemm_mfma(
    const int* __restrict__ flags, const void* __restrict__ Ap,
    const u16* __restrict__ Wt, const float* __restrict__ bias,
    u16* __restrict__ C, int M, int K) {
  bool fbf = flags[1] != 0;
  __shared__ u16 As[128 * 32];
  __shared__ u16 Bs[128 * 32];
  int tid = threadIdx.x;
  int rb = blockIdx.x * 128, cb = blockIdx.y * 128;
  int wave = tid >> 6, lane = tid & 63;
  int l15 = lane & 15, quad = lane >> 4;
  int mbase = (wave >> 1) * 64, nbase = (wave & 1) * 64;

  f32x4 acc[4][4];
#pragma unroll
  for (int mt = 0; mt < 4; ++mt)
#pragma unroll
    for (int nt = 0; nt < 4; ++nt)
#pragma unroll
      for (int r = 0; r < 4; ++r) acc[mt][nt][r] = 0.f;

  int srow0 = tid >> 2, schunk0 = tid & 3;
  int srow1 = (tid + 256) >> 2, schunk1 = (tid + 256) & 3;
  int gchunk0 = schunk0 ^ (srow0 & 3);
  int gchunk1 = schunk1 ^ (srow1 & 3);
  int arow0 = rb + srow0; if (arow0 >= M) arow0 = M - 1;
  int arow1 = rb + srow1; if (arow1 >= M) arow1 = M - 1;
  u16* asl0 = &As[srow0 * 32 + schunk0 * 8];
  u16* asl1 = &As[srow1 * 32 + schunk1 * 8];
  u16* bsl0 = &Bs[srow0 * 32 + schunk0 * 8];
  u16* bsl1 = &Bs[srow1 * 32 + schunk1 * 8];
  const u16* bsrc0 = Wt + (size_t)(cb + srow0) * K + gchunk0 * 8;
  const u16* bsrc1 = Wt + (size_t)(cb + srow1) * K + gchunk1 * 8;
  const bool adirect = AWS || fbf;
  const u16* asrc0 = adirect ? ((const u16*)Ap + (size_t)arow0 * K + gchunk0 * 8) : (const u16*)0;
  const u16* asrc1 = adirect ? ((const u16*)Ap + (size_t)arow1 * K + gchunk1 * 8) : (const u16*)0;

  for (int kk = 0; kk < K; kk += 32) {
    if (adirect) {
      gload_lds16(asrc0 + kk, asl0);
      gload_lds16(asrc1 + kk, asl1);
    } else {
      const float* A0 = (const float*)Ap + (size_t)arow0 * K + kk + gchunk0 * 8;
      const float* A1 = (const float*)Ap + (size_t)arow1 * K + kk + gchunk1 * 8;
      bf16x8 t0, t1;
#pragma unroll
      for (int i = 0; i < 8; ++i) { t0[i] = (short)f2bf(A0[i]); t1[i] = (short)f2bf(A1[i]); }
      *(bf16x8*)asl0 = t0;
      *(bf16x8*)asl1 = t1;
    }
    gload_lds16(bsrc0 + kk, bsl0);
    gload_lds16(bsrc1 + kk, bsl1);
    __syncthreads();

    bf16x8 bfrag[4];
#pragma unroll
    for (int nt = 0; nt < 4; ++nt) {
      int col = nbase + nt * 16 + l15;
      bfrag[nt] = *(const bf16x8*)&Bs[col * 32 + ((quad ^ (col & 3)) * 8)];
    }
#pragma unroll
    for (int mt = 0; mt < 4; ++mt) {
      int row = mbase + mt * 16 + l15;
      bf16x8 afrag = *(const bf16x8*)&As[row * 32 + ((quad ^ (row & 3)) * 8)];
#pragma unroll
      for (int nt = 0; nt < 4; ++nt)
        acc[mt][nt] = __builtin_amdgcn_mfma_f32_16x16x32_bf16(afrag, bfrag[nt], acc[mt][nt], 0, 0, 0);
    }
    __syncthreads();
  }

#pragma unroll
  for (int nt = 0; nt < 4; ++nt) {
    int gcol = cb + nbase + nt * 16 + l15;
    float bv = bias[gcol];
    int scol;
    if (gcol < 256) scol = gcol;
    else if (gcol < 512) { int cc = gcol - 256; scol = 256 + ((cc >> 2) << 3) + (cc & 3); }
    else if (gcol < 768) { int cc = gcol - 512; scol = 256 + ((cc >> 2) << 3) + 4 + (cc & 3); }
    else scol = gcol;
#pragma unroll
    for (int mt = 0; mt < 4; ++mt) {
#pragma unroll
      for (int r = 0; r < 4; ++r) {
        int grow = rb + mbase + mt * 16 + quad * 4 + r;
        if (grow < M) C[(size_t)grow * NB + scol] = f2bf(acc[mt][nt][r] + bv);
      }
    }
  }
}

// ---------------- fused alpha + softmax + aggregation + relu -----------------------
// v4: inline time-encode (kills the 41MB te_s stream + te_kernel entirely;
// VALU had 69% headroom), 10000 waves for latency-hiding TLP, static strided
// 2 nodes/wave, 1-ahead node prefetch, DPP reduce, direct exp2.
template <int DOY>
__global__ __launch_bounds__(256) void aggfused_kernel(
    const int* __restrict__ flags, const int* __restrict__ ssrc,
    const int* __restrict__ offsets, const float* __restrict__ stt,
    const float* __restrict__ divt,
    const u16* __restrict__ qkvp, const void* __restrict__ bt,
    u16* __restrict__ xout, const void* __restrict__ wc,
    float* __restrict__ ynode) {
  bool fbf = flags[1] != 0;
  int lane = threadIdx.x & 63;
  int c = lane * 4;
  int kvoff = 256 + lane * 8;

  // node-invariant per-lane data
  int i0 = (2 * lane) & 31;                 // this lane's two time-frequencies
  float dc0 = divt[i0], dc1 = divt[i0 + 1];
  float btv0 = ldf(bt, c + 0, fbf), btv1 = ldf(bt, c + 1, fbf);
  float btv2 = ldf(bt, c + 2, fbf), btv3 = ldf(bt, c + 3, fbf);
  float wcv0 = 0.f, wcv1 = 0.f, wcv2 = 0.f, wcv3 = 0.f;
  if (DOY) {
    wcv0 = ldf(wc, c + 0, fbf); wcv1 = ldf(wc, c + 1, fbf);
    wcv2 = ldf(wc, c + 2, fbf); wcv3 = ldf(wc, c + 3, fbf);
  }

  // first node of this wave; prefetch its data
  int n = blockIdx.x * 4 + (threadIdx.x >> 6);   // 0..9999
  int s0 = offsets[n], s1 = offsets[n + 1];
  int2 q2 = *(const int2*)(qkvp + (size_t)n * NB + c);
  int2 p2 = *(const int2*)(qkvp + (size_t)n * NB + 768 + c);

  while (n < NN) {
    // next node is statically known: issue its loads now, consume next iter
    int n1 = n + AGG_STRIDE;
    int n1c = (n1 < NN) ? n1 : 0;
    int s0n = offsets[n1c], s1n = offsets[n1c + 1];
    int2 q2n = *(const int2*)(qkvp + (size_t)n1c * NB + c);
    int2 p2n = *(const int2*)(qkvp + (size_t)n1c * NB + 768 + c);

    // ---- process node n (data already resident) ----
    float qx = bflo(q2.x), qy = bfhi(q2.x), qz = bflo(q2.y), qw = bfhi(q2.y);
    float px = bflo(p2.x) * LOG2E_8, py = bfhi(p2.x) * LOG2E_8;
    float pz = bflo(p2.y) * LOG2E_8, pw = bfhi(p2.y) * LOG2E_8;
    float pb = qx * btv0 + qy * btv1 + qz * btv2 + qw * btv3;
    float qb = dpp_row_allsum(pb) * LOG2E_8;
    float qsx = qx * LOG2E_8, qsy = qy * LOG2E_8;
    float qsz = qz * LOG2E_8, qsw = qw * LOG2E_8;

    float denom = 0.f, acc0 = 0.f, acc1 = 0.f, acc2 = 0.f, acc3 = 0.f;
    const int* sp = ssrc + s0;
    const float* tp = stt + s0;
    int ecnt = s1 - s0;
    int e = 0;
    if (ecnt >= 4) {
      int sA = sp[0], sB = sp[1], sC = sp[2], sD = sp[3];
      while (e + 4 <= ecnt) {
        int4 kvA = *(const int4*)(qkvp + ((unsigned)(sA << 10) + (unsigned)kvoff));
        int4 kvB = *(const int4*)(qkvp + ((unsigned)(sB << 10) + (unsigned)kvoff));
        int4 kvC = *(const int4*)(qkvp + ((unsigned)(sC << 10) + (unsigned)kvoff));
        int4 kvD = *(const int4*)(qkvp + ((unsigned)(sD << 10) + (unsigned)kvoff));
        float ttA = tp[e], ttB = tp[e + 1], ttC = tp[e + 2], ttD = tp[e + 3];
        int en = e + 4;
        if (en + 4 <= ecnt) {  // prefetch next quad's srcs (breaks src->kv chain)
          sA = sp[en]; sB = sp[en + 1]; sC = sp[en + 2]; sD = sp[en + 3];
        }
        edge_do(kvA, ttA, q2, dc0, dc1, qsx, qsy, qsz, qsw, px, py, pz, pw, qb,
                denom, acc0, acc1, acc2, acc3);
        edge_do(kvB, ttB, q2, dc0, dc1, qsx, qsy, qsz, qsw, px, py, pz, pw, qb,
                denom, acc0, acc1, acc2, acc3);
        edge_do(kvC, ttC, q2, dc0, dc1, qsx, qsy, qsz, qsw, px, py, pz, pw, qb,
                denom, acc0, acc1, acc2, acc3);
        edge_do(kvD, ttD, q2, dc0, dc1, qsx, qsy, qsz, qsw, px, py, pz, pw, qb,
                denom, acc0, acc1, acc2, acc3);
        e = en;
      }
    }
    for (; e < ecnt; ++e) {
      int s = sp[e];
      int4 kv = *(const int4*)(qkvp + ((unsigned)(s << 10) + (unsigned)kvoff));
      float tt = tp[e];
      edge_do(kv, tt, q2, dc0, dc1, qsx, qsy, qsz, qsw, px, py, pz, pw, qb,
              denom, acc0, acc1, acc2, acc3);
    }

    float inv = 1.f / (denom + 1e-16f);
    ushort4 r;
    r.x = f2bf(fmaxf(acc0 * inv, 0.f));
    r.y = f2bf(fmaxf(acc1 * inv, 0.f));
    r.z = f2bf(fmaxf(acc2 * inv, 0.f));
    r.w = f2bf(fmaxf(acc3 * inv, 0.f));
    *(ushort4*)(xout + (size_t)n * HC + c) = r;
    if (DOY) {
      float yv = bf2f(r.x) * wcv0 + bf2f(r.y) * wcv1 +
                 bf2f(r.z) * wcv2 + bf2f(r.w) * wcv3;
      yv = dpp_row_allsum(yv);
      yv += __shfl_xor(yv, 16);
      yv += __shfl_xor(yv, 32);
      if (lane == 0) ynode[n] = yv;
    }

    // rotate pipeline
    n = n1;
    s0 = s0n; s1 = s1n; q2 = q2n; p2 = p2n;
  }
}

// ---------------- out[e] = y[src] + y[dst] + bc ----------------
__global__ __launch_bounds__(256) void final2_kernel(
    const int* __restrict__ flags, const void* __restrict__ eidx,
    const float* __restrict__ y, const void* __restrict__ bc,
    void* __restrict__ out) {
  bool is64 = flags[0] != 0, fbf = flags[1] != 0;
  int e = blockIdx.x * 256 + threadIdx.x;
  if (e >= NE) return;
  int src = ldsrc(eidx, e, is64);
  int dst = lddst(eidx, e, is64);
  if ((unsigned)src >= NN) src = 0;
  if ((unsigned)dst >= NN) dst = 0;
  stout(out, e, y[src] + y[dst] + ldf(bc, 0, fbf), fbf);
}

extern "C" void kernel_launch(void* const* d_in, const int* in_sizes, int n_in,
                              void* d_out, int out_size, void* d_ws, size_t ws_size,
                              hipStream_t stream) {
  const void* eidx  = d_in[0];
  const void* rawt  = d_in[1];
  const void* noise = d_in[2];
  const void* nemb  = d_in[3];
  const void *wq1 = d_in[4],  *bq1 = d_in[5];
  const void *wk1 = d_in[6],  *bk1 = d_in[7];
  const void *wv1 = d_in[8],  *bv1 = d_in[9];
  const void *wt1 = d_in[10], *bt1 = d_in[11];
  const void *wq2 = d_in[12], *bq2 = d_in[13];
  const void *wk2 = d_in[14], *bk2 = d_in[15];
  const void *wv2 = d_in[16], *bv2 = d_in[17];
  const void *wt2 = d_in[18], *bt2 = d_in[19];
  const void *wcp = d_in[20], *bcp = d_in[21];

  char* ws = (char*)d_ws;
  size_t off = 0;
  auto alloc = [&](size_t bytes) -> void* {
    void* p = ws + off;
    off += (bytes + 255) & ~(size_t)255;
    return p;
  };
  int*   flags  = (int*)alloc(256);
  float* divt   = (float*)alloc(256);
  u16*   WtBig  = (u16*)alloc((size_t)NB * HC * 2);
  float* biasBig= (float*)alloc((size_t)NB * 4);
  u16*   qkvp   = (u16*)alloc((size_t)NN * NB * 2);
  u16*   x1     = (u16*)alloc((size_t)NN * HC * 2);
  u16*   x2     = (u16*)alloc((size_t)NN * HC * 2);
  float* ynode  = (float*)alloc((size_t)NN * 4);
  int* offsets  = (int*)alloc((size_t)(NN + 1) * 4);
  int* cursor   = (int*)alloc((size_t)NN * 4);
  int* bsum     = (int*)alloc(256 * 4);
  int* ssrc     = (int*)alloc((size_t)NE * 4);
  float* stt    = (float*)alloc((size_t)NE * 4);
  size_t need = off;

  int gN = (NN + 255) / 256, gE = (NE + 255) / 256;
  int nb = (NN + 255) / 256;

  if (ws_size < 1024) {
    raw_sentinel_kernel<<<gE, 256, 0, stream>>>((u16*)d_out);
    return;
  }
  devinit_kernel<<<1, 64, 0, stream>>>(eidx, nemb, flags, divt);
  if (need > ws_size) {
    sentinel_kernel<<<gE, 256, 0, stream>>>(flags, d_out);
    return;
  }

  // CSR by dst (+ sorted src / time)
  zero_kernel<<<gN, 256, 0, stream>>>(cursor, NN);
  hist_kernel<<<gE, 256, 0, stream>>>(flags, eidx, cursor);
  scan1_kernel<<<nb, 256, 0, stream>>>(cursor, offsets, bsum, NN);
  scan2_kernel<<<1, 256, 0, stream>>>(bsum, offsets, nb, NN);
  scan3_kernel<<<nb, 256, 0, stream>>>(offsets, bsum, cursor, NN);
  fill_kernel<<<gE, 256, 0, stream>>>(flags, eidx, rawt, noise, cursor, ssrc, stt);

  dim3 ggemm((NN + 127) / 128, NB / 128);   // 157 x 8
  dim3 gt1(NIN / 64, 4, 3), gt2(HC / 64, 4, 3);

  // ---- Layer 1 (A = raw node_emb, K=128) ----
  transw3_kernel<<<gt1, 256, 0, stream>>>(flags, wq1, wk1, wv1, WtBig, NIN);
  wcombbias_kernel<<<260, 256, 0, stream>>>(flags, wt1, WtBig, WtBig + (size_t)768 * NIN,
                                            bq1, bk1, bv1, biasBig, NIN);
  gemm_mfma<false><<<ggemm, 256, 0, stream>>>(flags, nemb, WtBig, biasBig, qkvp, NN, NIN);
  aggfused_kernel<0><<<AGG_BLOCKS, 256, 0, stream>>>(flags, ssrc, offsets, stt, divt,
                                                     qkvp, bt1, x1, wcp, ynode);

  // ---- Layer 2 (A = bf16 x1, K=256) ----
  transw3_kernel<<<gt2, 256, 0, stream>>>(flags, wq2, wk2, wv2, WtBig, HC);
  wcombbias_kernel<<<260, 256, 0, stream>>>(flags, wt2, WtBig, WtBig + (size_t)768 * HC,
                                            bq2, bk2, bv2, biasBig, HC);
  gemm_mfma<true><<<ggemm, 256, 0, stream>>>(flags, x1, WtBig, biasBig, qkvp, NN, HC);
  aggfused_kernel<1><<<AGG_BLOCKS, 256, 0, stream>>>(flags, ssrc, offsets, stt, divt,
                                                     qkvp, bt2, x2, wcp, ynode);

  // Edge scorer epilogue
  final2_kernel<<<gE, 256, 0, stream>>>(flags, eidx, ynode, bcp, d_out);
}

// Round 4
// 337.048 us; speedup vs baseline: 2.8375x; 1.0651x over previous
//
#include <hip/hip_runtime.h>
#include <hip/hip_fp16.h>
#include <math.h>

// Problem constants
#define NN   20000     // nodes
#define NE   320000    // edges
#define NIN  128       // node input dim
#define HC   256       // heads(4) * hidden(64)
#define NB   1024      // fused GEMM output width: [q | k | v | qproj] (identity layout)

// aggfused work distribution: 2500 blocks x 4 waves = 10000 waves, 2 strided
// nodes each (static, no atomics).
#define AGG_BLOCKS 2500
#define AGG_STRIDE 10000
#define LOG2E_8    0.18033688f   // log2(e)/8 -- folds the 1/sqrt(64) scale + exp->exp2

typedef unsigned short u16;
typedef __attribute__((ext_vector_type(8))) short bf16x8;
typedef __attribute__((ext_vector_type(4))) float f32x4;

__device__ __forceinline__ float bf2f(u16 u) {
  union { unsigned int i; float f; } x;
  x.i = ((unsigned int)u) << 16;
  return x.f;
}
__device__ __forceinline__ u16 f2bf(float f) {
  union { float f; unsigned int i; } x;
  x.f = f;
  unsigned int r = x.i + 0x7fffu + ((x.i >> 16) & 1u);
  return (u16)(r >> 16);
}
// packed-pair bf16 unpack: lo = <<16, hi = mask (1 VALU op each)
__device__ __forceinline__ float bflo(int v) {
  union { int i; float f; } x; x.i = v << 16; return x.f;
}
__device__ __forceinline__ float bfhi(int v) {
  union { int i; float f; } x; x.i = v & 0xffff0000; return x.f;
}

// dtype-flexible loads (flags detected on device each launch)
__device__ __forceinline__ float ldf(const void* p, int i, bool fbf) {
  return fbf ? bf2f(((const u16*)p)[i]) : ((const float*)p)[i];
}
__device__ __forceinline__ int ldsrc(const void* p, int e, bool is64) {
  const int* p32 = (const int*)p;
  return is64 ? p32[2 * e] : p32[e];
}
__device__ __forceinline__ int lddst(const void* p, int e, bool is64) {
  const int* p32 = (const int*)p;
  return is64 ? p32[2 * (NE + e)] : p32[NE + e];
}
__device__ __forceinline__ void stout(void* p, int i, float v, bool fbf) {
  if (fbf) ((u16*)p)[i] = f2bf(v);
  else ((float*)p)[i] = v;
}

// async global->LDS, 16B per lane
__device__ __forceinline__ void gload_lds16(const u16* g, u16* l) {
  __builtin_amdgcn_global_load_lds(
      (const __attribute__((address_space(1))) void*)g,
      (__attribute__((address_space(3))) void*)l, 16, 0, 0);
}

// 16-lane (row) all-sum via DPP row_ror adds: pure VALU, replaces 4 ds_bpermute.
__device__ __forceinline__ float dpp_row_allsum(float s) {
  union fi { float f; int i; };
  fi a, b;
  a.f = s;
  b.i = __builtin_amdgcn_update_dpp(0, a.i, 0x121, 0xf, 0xf, true); a.f += b.f;
  b.i = __builtin_amdgcn_update_dpp(0, a.i, 0x122, 0xf, 0xf, true); a.f += b.f;
  b.i = __builtin_amdgcn_update_dpp(0, a.i, 0x124, 0xf, 0xf, true); a.f += b.f;
  b.i = __builtin_amdgcn_update_dpp(0, a.i, 0x128, 0xf, 0xf, true); a.f += b.f;
  return a.f;
}

__device__ __forceinline__ float fexp2(float x) {
#if __has_builtin(__builtin_amdgcn_exp2f)
  return __builtin_amdgcn_exp2f(x);
#else
  return exp2f(x);
#endif
}

#if __has_builtin(__builtin_amdgcn_fdot2_f32_bf16)
#define HAS_BF16_DOT2 1
typedef __attribute__((ext_vector_type(2))) __bf16 bfv2_t;
__device__ __forceinline__ float qkdot2(int a, int b, float c) {
  return __builtin_amdgcn_fdot2_f32_bf16(__builtin_bit_cast(bfv2_t, a),
                                         __builtin_bit_cast(bfv2_t, b), c, false);
}
#else
#define HAS_BF16_DOT2 0
#endif

// one edge: inline time-encode (exact f32 Cody-Waite 1/2pi reduction of the
// f32 product arg = fl(tt*divt), matching the reference's sin(f32 arg)), then
// alpha partial -> DPP row reduce -> exp2 -> accumulate. No max tracking
// (|alpha| <= ~3 by construction, f32 exp2 safe by a huge margin).
__device__ __forceinline__ void edge_do(int2 kk, int2 vv, float tt, int2 q2,
    float dc0, float dc1,
    float qsx, float qsy, float qsz, float qsw,
    float px, float py, float pz, float pw, float qb,
    float& denom, float& a0, float& a1, float& a2, float& a3) {
  const float CH = 0.15915494f;                                    // f32(1/2pi)
  const float CL = (float)(0.15915494309189535 - (double)0.15915494f);
  float x0 = tt * dc0, x1 = tt * dc1;     // = reference's f32 arg
  float p0 = x0 * CH, p1 = x1 * CH;
  float e0 = fmaf(x0, CH, -p0), e1 = fmaf(x1, CH, -p1);
  e0 = fmaf(x0, CL, e0);  e1 = fmaf(x1, CL, e1);
  float fr0 = (p0 - rintf(p0)) + e0;      // revolutions, |fr| <= ~0.5
  float fr1 = (p1 - rintf(p1)) + e1;
  float sv0 = __builtin_amdgcn_sinf(fr0), cv0 = __builtin_amdgcn_cosf(fr0);
  float sv1 = __builtin_amdgcn_sinf(fr1), cv1 = __builtin_amdgcn_cosf(fr1);
  float stp = sv0 * px + cv0 * py + sv1 * pz + cv1 * pw;
#if HAS_BF16_DOT2
  float sqk = qkdot2(kk.y, q2.y, qkdot2(kk.x, q2.x, 0.f));
  float partial = sqk * LOG2E_8 + stp;
#else
  float partial = stp + qsx * bflo(kk.x) + qsy * bfhi(kk.x) +
                  qsz * bflo(kk.y) + qsw * bfhi(kk.y);
#endif
  float a = dpp_row_allsum(partial) + qb;
  float ea = fexp2(a);
  denom += ea;
  a0 = fmaf(ea, bflo(vv.x), a0);
  a1 = fmaf(ea, bfhi(vv.x), a1);
  a2 = fmaf(ea, bflo(vv.y), a2);
  a3 = fmaf(ea, bfhi(vv.y), a3);
}

// ---------------- detection + div_term init ----------------
__global__ void devinit_kernel(const void* __restrict__ eidx,
                               const void* __restrict__ nemb,
                               int* __restrict__ flags, float* __restrict__ divt) {
  int lane = threadIdx.x;
  if (lane < 32) {
    const float c32 = (float)(-0.14391156831212787);
    float prod = (float)(2 * lane) * c32;
    divt[lane] = (float)exp((double)prod);
  }
  if (lane == 0) {
    const int* p32 = (const int*)eidx;
    int is64 = 1;
    for (int i = 1; i < 128; i += 2)
      if (p32[i] != 0) { is64 = 0; break; }
    const u16* q16 = (const u16*)nemb;
    int fbf = 1;
    for (int i = 0; i < 128; i += 2) {
      unsigned e = (q16[i] >> 7) & 0xFF;
      if (e < 90 || e > 140) { fbf = 0; break; }
    }
    flags[0] = is64;
    flags[1] = fbf;
  }
}

__global__ void sentinel_kernel(const int* __restrict__ flags, void* __restrict__ out) {
  int i = blockIdx.x * 256 + threadIdx.x;
  if (i < NE) stout(out, i, 3000.0f, flags[1] != 0);
}
__global__ void raw_sentinel_kernel(u16* __restrict__ out) {
  int i = blockIdx.x * 256 + threadIdx.x;
  if (i < NE) out[i] = f2bf(3000.0f);
}

// ---------------- CSR build ----------------
__global__ void zero_kernel(int* __restrict__ p, int n) {
  int i = blockIdx.x * 256 + threadIdx.x;
  if (i < n) p[i] = 0;
}

__global__ void hist_kernel(const int* __restrict__ flags, const void* __restrict__ eidx,
                            int* __restrict__ cnt) {
  bool is64 = flags[0] != 0;
  int e = blockIdx.x * 256 + threadIdx.x;
  if (e < NE) {
    int d = lddst(eidx, e, is64);
    if ((unsigned)d < NN) atomicAdd(&cnt[d], 1);
  }
}

__global__ void scan1_kernel(const int* __restrict__ cnt, int* __restrict__ offs,
                             int* __restrict__ bsum, int n) {
  __shared__ int s[256];
  int b = blockIdx.x, t = threadIdx.x, i = b * 256 + t;
  int x = (i < n) ? cnt[i] : 0;
  s[t] = x;
  __syncthreads();
  for (int off = 1; off < 256; off <<= 1) {
    int y = (t >= off) ? s[t - off] : 0;
    __syncthreads();
    s[t] += y;
    __syncthreads();
  }
  if (i < n) offs[i] = s[t] - x;
  if (t == 255) bsum[b] = s[t];
}

__global__ void scan2_kernel(int* __restrict__ bsum, int* __restrict__ offs,
                             int nb, int n) {
  __shared__ int s[256];
  int t = threadIdx.x;
  int x = (t < nb) ? bsum[t] : 0;
  s[t] = x;
  __syncthreads();
  for (int off = 1; off < 256; off <<= 1) {
    int y = (t >= off) ? s[t - off] : 0;
    __syncthreads();
    s[t] += y;
    __syncthreads();
  }
  if (t < nb) bsum[t] = s[t] - x;
  if (t == 255) offs[n] = s[t];
}

__global__ void scan3_kernel(int* __restrict__ offs, const int* __restrict__ bsum,
                             int* __restrict__ cursor, int n) {
  int i = blockIdx.x * 256 + threadIdx.x;
  if (i < n) {
    int v = offs[i] + bsum[blockIdx.x];
    offs[i] = v;
    cursor[i] = v;
  }
}

__global__ void fill_kernel(const int* __restrict__ flags, const void* __restrict__ eidx,
                            const void* __restrict__ rawt, const void* __restrict__ noise,
                            int* __restrict__ cursor, int* __restrict__ ssrc,
                            float* __restrict__ stt) {
  bool is64 = flags[0] != 0, fbf = flags[1] != 0;
  int e = blockIdx.x * 256 + threadIdx.x;
  if (e < NE) {
    int d = lddst(eidx, e, is64);
    if ((unsigned)d < NN) {
      int pos = atomicAdd(&cursor[d], 1);
      if ((unsigned)pos < NE) {
        int src = ldsrc(eidx, e, is64);
        if ((unsigned)src >= NN) src = 0;
        ssrc[pos] = src;
        stt[pos] = ldf(rawt, e, fbf) + ldf(noise, e, fbf);
      }
    }
  }
}

// ---------------- merged weight transpose: 3 matrices -> WtBig rows 0/256/512 -----
__global__ void transw3_kernel(const int* __restrict__ flags, const void* __restrict__ W0,
                               const void* __restrict__ W1, const void* __restrict__ W2,
                               u16* __restrict__ WtBig, int K) {
  bool fbf = flags[1] != 0;
  __shared__ u16 tile[64][65];
  int z = blockIdx.z;
  const void* W = (z == 0) ? W0 : (z == 1) ? W1 : W2;
  u16* dst = WtBig + (size_t)z * 256 * K;
  int kb = blockIdx.x * 64, cb = blockIdx.y * 64;
  int tx = threadIdx.x & 63, ty = threadIdx.x >> 6;
  for (int i = ty; i < 64; i += 4)
    tile[tx][i] = f2bf(ldf(W, (kb + i) * HC + cb + tx, fbf));
  __syncthreads();
  for (int i = ty; i < 64; i += 4)
    dst[(size_t)(cb + i) * K + kb + tx] = tile[i][tx];
}

// ---------------- wcomb + biasBig merged ----------------
__global__ void wcombbias_kernel(const int* __restrict__ flags, const void* __restrict__ wt,
                                 const u16* __restrict__ Wqt, u16* __restrict__ Wout,
                                 const void* __restrict__ bq, const void* __restrict__ bk,
                                 const void* __restrict__ bv, float* __restrict__ biasBig,
                                 int K) {
  bool fbf = flags[1] != 0;
  int b = blockIdx.x, t = threadIdx.x;
  if (b < 256) {
    __shared__ float wrow[64];
    int j = b, h = j >> 6;
    if (t < 64) wrow[t] = ldf(wt, (j & 63) * HC + h * 64 + t, fbf);
    __syncthreads();
    if (t < K) {
      float s = 0.f;
#pragma unroll 8
      for (int mm = 0; mm < 64; ++mm)
        s += wrow[mm] * bf2f(Wqt[(size_t)(h * 64 + mm) * K + t]);
      Wout[(size_t)j * K + t] = f2bf(s);
    }
  } else if (b < 259) {
    int bb = b - 256;
    const void* p = (bb == 0) ? bq : (bb == 1) ? bk : bv;
    biasBig[bb * 256 + t] = ldf(p, t, fbf);
  } else {
    int j = t, h = j >> 6;
    float s = 0.f;
    for (int mm = 0; mm < 64; ++mm)
      s += ldf(bq, h * 64 + mm, fbf) * ldf(wt, (j & 63) * HC + h * 64 + mm, fbf);
    biasBig[768 + j] = s;
  }
}

// ---------------- fused MFMA GEMM — 128x128 tile, double-buffered ----------------
// v2: (a) LDS double-buffer with STAGE(t+1) issued before COMPUTE(t) and ONE
// barrier per K-step (T3 minimum 2-phase; old code exposed full staging
// latency each of the 4-8 K-steps -> MfmaUtil 6.7%); (b) identity output
// layout [q|k|v|qp] -- the old kv-interleave made col-tile-2/3 BLOCKS write
// alternating 8B granules of the same 64B lines => RMW (WRITE 81MB vs 41 ideal).
template <bool AWS>
__global__ __launch_bounds__(256) void gemm_mfma(
    const int* __restrict__ flags, const void* __restrict__ Ap,
    const u16* __restrict__ Wt, const float* __restrict__ bias,
    u16* __restrict__ C, int M, int K) {
  bool fbf = flags[1] != 0;
  __shared__ u16 As[2][128 * 32];
  __shared__ u16 Bs[2][128 * 32];
  int tid = threadIdx.x;
  int rb = blockIdx.x * 128, cb = blockIdx.y * 128;
  int wave = tid >> 6, lane = tid & 63;
  int l15 = lane & 15, quad = lane >> 4;
  int mbase = (wave >> 1) * 64, nbase = (wave & 1) * 64;

  f32x4 acc[4][4];
#pragma unroll
  for (int mt = 0; mt < 4; ++mt)
#pragma unroll
    for (int nt = 0; nt < 4; ++nt)
#pragma unroll
      for (int r = 0; r < 4; ++r) acc[mt][nt][r] = 0.f;

  // staging slots: sidx = tid and tid+256; srow = sidx>>2 (0..127), schunk = sidx&3
  int srow0 = tid >> 2, schunk0 = tid & 3;
  int srow1 = (tid + 256) >> 2, schunk1 = (tid + 256) & 3;
  int gchunk0 = schunk0 ^ (srow0 & 3);
  int gchunk1 = schunk1 ^ (srow1 & 3);
  int arow0 = rb + srow0; if (arow0 >= M) arow0 = M - 1;
  int arow1 = rb + srow1; if (arow1 >= M) arow1 = M - 1;
  int slo0 = srow0 * 32 + schunk0 * 8;
  int slo1 = srow1 * 32 + schunk1 * 8;
  const u16* bsrc0 = Wt + (size_t)(cb + srow0) * K + gchunk0 * 8;
  const u16* bsrc1 = Wt + (size_t)(cb + srow1) * K + gchunk1 * 8;
  const bool adirect = AWS || fbf;
  const u16* asrc0 = adirect ? ((const u16*)Ap + (size_t)arow0 * K + gchunk0 * 8) : (const u16*)0;
  const u16* asrc1 = adirect ? ((const u16*)Ap + (size_t)arow1 * K + gchunk1 * 8) : (const u16*)0;
  const float* afsrc0 = (const float*)Ap + (size_t)arow0 * K + gchunk0 * 8;
  const float* afsrc1 = (const float*)Ap + (size_t)arow1 * K + gchunk1 * 8;

  auto STAGE = [&](int b, int kk) {
    if (adirect) {
      gload_lds16(asrc0 + kk, &As[b][slo0]);
      gload_lds16(asrc1 + kk, &As[b][slo1]);
    } else {
      const float* A0 = afsrc0 + kk;
      const float* A1 = afsrc1 + kk;
      bf16x8 t0, t1;
#pragma unroll
      for (int i = 0; i < 8; ++i) { t0[i] = (short)f2bf(A0[i]); t1[i] = (short)f2bf(A1[i]); }
      *(bf16x8*)&As[b][slo0] = t0;
      *(bf16x8*)&As[b][slo1] = t1;
    }
    gload_lds16(bsrc0 + kk, &Bs[b][slo0]);
    gload_lds16(bsrc1 + kk, &Bs[b][slo1]);
  };

  auto COMPUTE = [&](int b) {
    bf16x8 bfrag[4];
#pragma unroll
    for (int nt = 0; nt < 4; ++nt) {
      int col = nbase + nt * 16 + l15;
      bfrag[nt] = *(const bf16x8*)&Bs[b][col * 32 + ((quad ^ (col & 3)) * 8)];
    }
#pragma unroll
    for (int mt = 0; mt < 4; ++mt) {
      int row = mbase + mt * 16 + l15;
      bf16x8 afrag = *(const bf16x8*)&As[b][row * 32 + ((quad ^ (row & 3)) * 8)];
#pragma unroll
      for (int nt = 0; nt < 4; ++nt)
        acc[mt][nt] = __builtin_amdgcn_mfma_f32_16x16x32_bf16(afrag, bfrag[nt], acc[mt][nt], 0, 0, 0);
    }
  };

  STAGE(0, 0);
  __syncthreads();            // buf0 ready (barrier drains vmcnt)
  int cur = 0;
  for (int kk = 32; kk < K; kk += 32) {
    STAGE(cur ^ 1, kk);       // async loads for next step, in flight under COMPUTE
    COMPUTE(cur);
    __syncthreads();          // next buf ready + everyone done with cur
    cur ^= 1;
  }
  COMPUTE(cur);

  // epilogue: identity scol = gcol; nt-inner order so a row's 4 chunks (128B)
  // are issued back-to-back for line coalescing.
  float bvv[4];
#pragma unroll
  for (int nt = 0; nt < 4; ++nt) bvv[nt] = bias[cb + nbase + nt * 16 + l15];
#pragma unroll
  for (int mt = 0; mt < 4; ++mt) {
#pragma unroll
    for (int r = 0; r < 4; ++r) {
      int grow = rb + mbase + mt * 16 + quad * 4 + r;
      if (grow < M) {
        size_t rowo = (size_t)grow * NB + cb + nbase + l15;
#pragma unroll
        for (int nt = 0; nt < 4; ++nt)
          C[rowo + nt * 16] = f2bf(acc[mt][nt][r] + bvv[nt]);
      }
    }
  }
}

// ---------------- fused alpha + softmax + aggregation + relu -----------------------
// v5: identity qkvp layout -> k and v are two 8B loads at imm offsets off one
// src base (same gathered cache lines as the old 16B interleave granule).
template <int DOY>
__global__ __launch_bounds__(256) void aggfused_kernel(
    const int* __restrict__ flags, const int* __restrict__ ssrc,
    const int* __restrict__ offsets, const float* __restrict__ stt,
    const float* __restrict__ divt,
    const u16* __restrict__ qkvp, const void* __restrict__ bt,
    u16* __restrict__ xout, const void* __restrict__ wc,
    float* __restrict__ ynode) {
  bool fbf = flags[1] != 0;
  int lane = threadIdx.x & 63;
  int c = lane * 4;

  // node-invariant per-lane data
  int i0 = (2 * lane) & 31;                 // this lane's two time-frequencies
  float dc0 = divt[i0], dc1 = divt[i0 + 1];
  float btv0 = ldf(bt, c + 0, fbf), btv1 = ldf(bt, c + 1, fbf);
  float btv2 = ldf(bt, c + 2, fbf), btv3 = ldf(bt, c + 3, fbf);
  float wcv0 = 0.f, wcv1 = 0.f, wcv2 = 0.f, wcv3 = 0.f;
  if (DOY) {
    wcv0 = ldf(wc, c + 0, fbf); wcv1 = ldf(wc, c + 1, fbf);
    wcv2 = ldf(wc, c + 2, fbf); wcv3 = ldf(wc, c + 3, fbf);
  }

  // first node of this wave; prefetch its data
  int n = blockIdx.x * 4 + (threadIdx.x >> 6);   // 0..9999
  int s0 = offsets[n], s1 = offsets[n + 1];
  int2 q2 = *(const int2*)(qkvp + (size_t)n * NB + c);
  int2 p2 = *(const int2*)(qkvp + (size_t)n * NB + 768 + c);

  while (n < NN) {
    // next node is statically known: issue its loads now, consume next iter
    int n1 = n + AGG_STRIDE;
    int n1c = (n1 < NN) ? n1 : 0;
    int s0n = offsets[n1c], s1n = offsets[n1c + 1];
    int2 q2n = *(const int2*)(qkvp + (size_t)n1c * NB + c);
    int2 p2n = *(const int2*)(qkvp + (size_t)n1c * NB + 768 + c);

    // ---- process node n (data already resident) ----
    float qx = bflo(q2.x), qy = bfhi(q2.x), qz = bflo(q2.y), qw = bfhi(q2.y);
    float px = bflo(p2.x) * LOG2E_8, py = bfhi(p2.x) * LOG2E_8;
    float pz = bflo(p2.y) * LOG2E_8, pw = bfhi(p2.y) * LOG2E_8;
    float pb = qx * btv0 + qy * btv1 + qz * btv2 + qw * btv3;
    float qb = dpp_row_allsum(pb) * LOG2E_8;
    float qsx = qx * LOG2E_8, qsy = qy * LOG2E_8;
    float qsz = qz * LOG2E_8, qsw = qw * LOG2E_8;

    float denom = 0.f, acc0 = 0.f, acc1 = 0.f, acc2 = 0.f, acc3 = 0.f;
    const int* sp = ssrc + s0;
    const float* tp = stt + s0;
    int ecnt = s1 - s0;
    int e = 0;
    if (ecnt >= 4) {
      int sA = sp[0], sB = sp[1], sC = sp[2], sD = sp[3];
      while (e + 4 <= ecnt) {
        const u16* bA = qkvp + ((unsigned)sA << 10) + c;
        const u16* bB = qkvp + ((unsigned)sB << 10) + c;
        const u16* bC = qkvp + ((unsigned)sC << 10) + c;
        const u16* bD = qkvp + ((unsigned)sD << 10) + c;
        int2 kA = *(const int2*)(bA + 256), vA = *(const int2*)(bA + 512);
        int2 kB = *(const int2*)(bB + 256), vB = *(const int2*)(bB + 512);
        int2 kC = *(const int2*)(bC + 256), vC = *(const int2*)(bC + 512);
        int2 kD = *(const int2*)(bD + 256), vD = *(const int2*)(bD + 512);
        float ttA = tp[e], ttB = tp[e + 1], ttC = tp[e + 2], ttD = tp[e + 3];
        int en = e + 4;
        if (en + 4 <= ecnt) {  // prefetch next quad's srcs (breaks src->kv chain)
          sA = sp[en]; sB = sp[en + 1]; sC = sp[en + 2]; sD = sp[en + 3];
        }
        edge_do(kA, vA, ttA, q2, dc0, dc1, qsx, qsy, qsz, qsw, px, py, pz, pw, qb,
                denom, acc0, acc1, acc2, acc3);
        edge_do(kB, vB, ttB, q2, dc0, dc1, qsx, qsy, qsz, qsw, px, py, pz, pw, qb,
                denom, acc0, acc1, acc2, acc3);
        edge_do(kC, vC, ttC, q2, dc0, dc1, qsx, qsy, qsz, qsw, px, py, pz, pw, qb,
                denom, acc0, acc1, acc2, acc3);
        edge_do(kD, vD, ttD, q2, dc0, dc1, qsx, qsy, qsz, qsw, px, py, pz, pw, qb,
                denom, acc0, acc1, acc2, acc3);
        e = en;
      }
    }
    for (; e < ecnt; ++e) {
      int s = sp[e];
      const u16* bS = qkvp + ((unsigned)s << 10) + c;
      int2 kS = *(const int2*)(bS + 256), vS = *(const int2*)(bS + 512);
      float tt = tp[e];
      edge_do(kS, vS, tt, q2, dc0, dc1, qsx, qsy, qsz, qsw, px, py, pz, pw, qb,
              denom, acc0, acc1, acc2, acc3);
    }

    float inv = 1.f / (denom + 1e-16f);
    ushort4 r;
    r.x = f2bf(fmaxf(acc0 * inv, 0.f));
    r.y = f2bf(fmaxf(acc1 * inv, 0.f));
    r.z = f2bf(fmaxf(acc2 * inv, 0.f));
    r.w = f2bf(fmaxf(acc3 * inv, 0.f));
    *(ushort4*)(xout + (size_t)n * HC + c) = r;
    if (DOY) {
      float yv = bf2f(r.x) * wcv0 + bf2f(r.y) * wcv1 +
                 bf2f(r.z) * wcv2 + bf2f(r.w) * wcv3;
      yv = dpp_row_allsum(yv);
      yv += __shfl_xor(yv, 16);
      yv += __shfl_xor(yv, 32);
      if (lane == 0) ynode[n] = yv;
    }

    // rotate pipeline
    n = n1;
    s0 = s0n; s1 = s1n; q2 = q2n; p2 = p2n;
  }
}

// ---------------- out[e] = y[src] + y[dst] + bc ----------------
__global__ __launch_bounds__(256) void final2_kernel(
    const int* __restrict__ flags, const void* __restrict__ eidx,
    const float* __restrict__ y, const void* __restrict__ bc,
    void* __restrict__ out) {
  bool is64 = flags[0] != 0, fbf = flags[1] != 0;
  int e = blockIdx.x * 256 + threadIdx.x;
  if (e >= NE) return;
  int src = ldsrc(eidx, e, is64);
  int dst = lddst(eidx, e, is64);
  if ((unsigned)src >= NN) src = 0;
  if ((unsigned)dst >= NN) dst = 0;
  stout(out, e, y[src] + y[dst] + ldf(bc, 0, fbf), fbf);
}

extern "C" void kernel_launch(void* const* d_in, const int* in_sizes, int n_in,
                              void* d_out, int out_size, void* d_ws, size_t ws_size,
                              hipStream_t stream) {
  const void* eidx  = d_in[0];
  const void* rawt  = d_in[1];
  const void* noise = d_in[2];
  const void* nemb  = d_in[3];
  const void *wq1 = d_in[4],  *bq1 = d_in[5];
  const void *wk1 = d_in[6],  *bk1 = d_in[7];
  const void *wv1 = d_in[8],  *bv1 = d_in[9];
  const void *wt1 = d_in[10], *bt1 = d_in[11];
  const void *wq2 = d_in[12], *bq2 = d_in[13];
  const void *wk2 = d_in[14], *bk2 = d_in[15];
  const void *wv2 = d_in[16], *bv2 = d_in[17];
  const void *wt2 = d_in[18], *bt2 = d_in[19];
  const void *wcp = d_in[20], *bcp = d_in[21];

  char* ws = (char*)d_ws;
  size_t off = 0;
  auto alloc = [&](size_t bytes) -> void* {
    void* p = ws + off;
    off += (bytes + 255) & ~(size_t)255;
    return p;
  };
  int*   flags  = (int*)alloc(256);
  float* divt   = (float*)alloc(256);
  u16*   WtBig  = (u16*)alloc((size_t)NB * HC * 2);
  float* biasBig= (float*)alloc((size_t)NB * 4);
  u16*   qkvp   = (u16*)alloc((size_t)NN * NB * 2);
  u16*   x1     = (u16*)alloc((size_t)NN * HC * 2);
  u16*   x2     = (u16*)alloc((size_t)NN * HC * 2);
  float* ynode  = (float*)alloc((size_t)NN * 4);
  int* offsets  = (int*)alloc((size_t)(NN + 1) * 4);
  int* cursor   = (int*)alloc((size_t)NN * 4);
  int* bsum     = (int*)alloc(256 * 4);
  int* ssrc     = (int*)alloc((size_t)NE * 4);
  float* stt    = (float*)alloc((size_t)NE * 4);
  size_t need = off;

  int gN = (NN + 255) / 256, gE = (NE + 255) / 256;
  int nb = (NN + 255) / 256;

  if (ws_size < 1024) {
    raw_sentinel_kernel<<<gE, 256, 0, stream>>>((u16*)d_out);
    return;
  }
  devinit_kernel<<<1, 64, 0, stream>>>(eidx, nemb, flags, divt);
  if (need > ws_size) {
    sentinel_kernel<<<gE, 256, 0, stream>>>(flags, d_out);
    return;
  }

  // CSR by dst (+ sorted src / time)
  zero_kernel<<<gN, 256, 0, stream>>>(cursor, NN);
  hist_kernel<<<gE, 256, 0, stream>>>(flags, eidx, cursor);
  scan1_kernel<<<nb, 256, 0, stream>>>(cursor, offsets, bsum, NN);
  scan2_kernel<<<1, 256, 0, stream>>>(bsum, offsets, nb, NN);
  scan3_kernel<<<nb, 256, 0, stream>>>(offsets, bsum, cursor, NN);
  fill_kernel<<<gE, 256, 0, stream>>>(flags, eidx, rawt, noise, cursor, ssrc, stt);

  dim3 ggemm((NN + 127) / 128, NB / 128);   // 157 x 8
  dim3 gt1(NIN / 64, 4, 3), gt2(HC / 64, 4, 3);

  // ---- Layer 1 (A = raw node_emb, K=128) ----
  transw3_kernel<<<gt1, 256, 0, stream>>>(flags, wq1, wk1, wv1, WtBig, NIN);
  wcombbias_kernel<<<260, 256, 0, stream>>>(flags, wt1, WtBig, WtBig + (size_t)768 * NIN,
                                            bq1, bk1, bv1, biasBig, NIN);
  gemm_mfma<false><<<ggemm, 256, 0, stream>>>(flags, nemb, WtBig, biasBig, qkvp, NN, NIN);
  aggfused_kernel<0><<<AGG_BLOCKS, 256, 0, stream>>>(flags, ssrc, offsets, stt, divt,
                                                     qkvp, bt1, x1, wcp, ynode);

  // ---- Layer 2 (A = bf16 x1, K=256) ----
  transw3_kernel<<<gt2, 256, 0, stream>>>(flags, wq2, wk2, wv2, WtBig, HC);
  wcombbias_kernel<<<260, 256, 0, stream>>>(flags, wt2, WtBig, WtBig + (size_t)768 * HC,
                                            bq2, bk2, bv2, biasBig, HC);
  gemm_mfma<true><<<ggemm, 256, 0, stream>>>(flags, x1, WtBig, biasBig, qkvp, NN, HC);
  aggfused_kernel<1><<<AGG_BLOCKS, 256, 0, stream>>>(flags, ssrc, offsets, stt, divt,
                                                     qkvp, bt2, x2, wcp, ynode);

  // Edge scorer epilogue
  final2_kernel<<<gE, 256, 0, stream>>>(flags, eidx, ynode, bcp, d_out);
}

// Round 5
// 325.157 us; speedup vs baseline: 2.9412x; 1.0366x over previous
//
#include <hip/hip_runtime.h>
#include <hip/hip_fp16.h>
#include <math.h>

// Problem constants
#define NN   20000     // nodes
#define NE   320000    // edges
#define NIN  128       // node input dim
#define HC   256       // heads(4) * hidden(64)
#define NB   1024      // fused GEMM output width: [q | k | v | qproj] (identity layout)

// aggfused work distribution: 2500 blocks x 4 waves = 10000 waves, 2 strided
// nodes each (static, no atomics).
#define AGG_BLOCKS 2500
#define AGG_STRIDE 10000
#define LOG2E_8    0.18033688f   // log2(e)/8 -- folds the 1/sqrt(64) scale + exp->exp2

// gemm grid: 8 XCD chunks x 20 row-slots x 8 col-tiles = 1280 blocks (1D)
#define GEMM_BLOCKS 1280
#define GEMM_RT     157        // row tiles = ceil(20000/128)

typedef unsigned short u16;
typedef __attribute__((ext_vector_type(8))) short bf16x8;
typedef __attribute__((ext_vector_type(4))) float f32x4;

__device__ __forceinline__ float bf2f(u16 u) {
  union { unsigned int i; float f; } x;
  x.i = ((unsigned int)u) << 16;
  return x.f;
}
__device__ __forceinline__ u16 f2bf(float f) {
  union { float f; unsigned int i; } x;
  x.f = f;
  unsigned int r = x.i + 0x7fffu + ((x.i >> 16) & 1u);
  return (u16)(r >> 16);
}
// packed-pair bf16 unpack: lo = <<16, hi = mask (1 VALU op each)
__device__ __forceinline__ float bflo(int v) {
  union { int i; float f; } x; x.i = v << 16; return x.f;
}
__device__ __forceinline__ float bfhi(int v) {
  union { int i; float f; } x; x.i = v & 0xffff0000; return x.f;
}

// dtype-flexible loads (flags detected on device each launch)
__device__ __forceinline__ float ldf(const void* p, int i, bool fbf) {
  return fbf ? bf2f(((const u16*)p)[i]) : ((const float*)p)[i];
}
__device__ __forceinline__ int ldsrc(const void* p, int e, bool is64) {
  const int* p32 = (const int*)p;
  return is64 ? p32[2 * e] : p32[e];
}
__device__ __forceinline__ int lddst(const void* p, int e, bool is64) {
  const int* p32 = (const int*)p;
  return is64 ? p32[2 * (NE + e)] : p32[NE + e];
}
__device__ __forceinline__ void stout(void* p, int i, float v, bool fbf) {
  if (fbf) ((u16*)p)[i] = f2bf(v);
  else ((float*)p)[i] = v;
}

// async global->LDS, 16B per lane
__device__ __forceinline__ void gload_lds16(const u16* g, u16* l) {
  __builtin_amdgcn_global_load_lds(
      (const __attribute__((address_space(1))) void*)g,
      (__attribute__((address_space(3))) void*)l, 16, 0, 0);
}

// 16-lane (row) all-sum via DPP row_ror adds: pure VALU, replaces 4 ds_bpermute.
__device__ __forceinline__ float dpp_row_allsum(float s) {
  union fi { float f; int i; };
  fi a, b;
  a.f = s;
  b.i = __builtin_amdgcn_update_dpp(0, a.i, 0x121, 0xf, 0xf, true); a.f += b.f;
  b.i = __builtin_amdgcn_update_dpp(0, a.i, 0x122, 0xf, 0xf, true); a.f += b.f;
  b.i = __builtin_amdgcn_update_dpp(0, a.i, 0x124, 0xf, 0xf, true); a.f += b.f;
  b.i = __builtin_amdgcn_update_dpp(0, a.i, 0x128, 0xf, 0xf, true); a.f += b.f;
  return a.f;
}

__device__ __forceinline__ float fexp2(float x) {
#if __has_builtin(__builtin_amdgcn_exp2f)
  return __builtin_amdgcn_exp2f(x);
#else
  return exp2f(x);
#endif
}

#if __has_builtin(__builtin_amdgcn_fdot2_f32_bf16)
#define HAS_BF16_DOT2 1
typedef __attribute__((ext_vector_type(2))) __bf16 bfv2_t;
__device__ __forceinline__ float qkdot2(int a, int b, float c) {
  return __builtin_amdgcn_fdot2_f32_bf16(__builtin_bit_cast(bfv2_t, a),
                                         __builtin_bit_cast(bfv2_t, b), c, false);
}
#else
#define HAS_BF16_DOT2 0
#endif

// one edge: inline time-encode (exact f32 Cody-Waite 1/2pi reduction of the
// f32 product arg = fl(tt*divt), matching the reference's sin(f32 arg)), then
// alpha partial -> DPP row reduce -> exp2 -> accumulate. No max tracking
// (|alpha| <= ~3 by construction, f32 exp2 safe by a huge margin).
__device__ __forceinline__ void edge_do(int2 kk, int2 vv, float tt, int2 q2,
    float dc0, float dc1,
    float qsx, float qsy, float qsz, float qsw,
    float px, float py, float pz, float pw, float qb,
    float& denom, float& a0, float& a1, float& a2, float& a3) {
  const float CH = 0.15915494f;                                    // f32(1/2pi)
  const float CL = (float)(0.15915494309189535 - (double)0.15915494f);
  float x0 = tt * dc0, x1 = tt * dc1;     // = reference's f32 arg
  float p0 = x0 * CH, p1 = x1 * CH;
  float e0 = fmaf(x0, CH, -p0), e1 = fmaf(x1, CH, -p1);
  e0 = fmaf(x0, CL, e0);  e1 = fmaf(x1, CL, e1);
  float fr0 = (p0 - rintf(p0)) + e0;      // revolutions, |fr| <= ~0.5
  float fr1 = (p1 - rintf(p1)) + e1;
  float sv0 = __builtin_amdgcn_sinf(fr0), cv0 = __builtin_amdgcn_cosf(fr0);
  float sv1 = __builtin_amdgcn_sinf(fr1), cv1 = __builtin_amdgcn_cosf(fr1);
  float stp = sv0 * px + cv0 * py + sv1 * pz + cv1 * pw;
#if HAS_BF16_DOT2
  float sqk = qkdot2(kk.y, q2.y, qkdot2(kk.x, q2.x, 0.f));
  float partial = sqk * LOG2E_8 + stp;
#else
  float partial = stp + qsx * bflo(kk.x) + qsy * bfhi(kk.x) +
                  qsz * bflo(kk.y) + qsw * bfhi(kk.y);
#endif
  float a = dpp_row_allsum(partial) + qb;
  float ea = fexp2(a);
  denom += ea;
  a0 = fmaf(ea, bflo(vv.x), a0);
  a1 = fmaf(ea, bfhi(vv.x), a1);
  a2 = fmaf(ea, bflo(vv.y), a2);
  a3 = fmaf(ea, bfhi(vv.y), a3);
}

// ---------------- detection + div_term init ----------------
__global__ void devinit_kernel(const void* __restrict__ eidx,
                               const void* __restrict__ nemb,
                               int* __restrict__ flags, float* __restrict__ divt) {
  int lane = threadIdx.x;
  if (lane < 32) {
    const float c32 = (float)(-0.14391156831212787);
    float prod = (float)(2 * lane) * c32;
    divt[lane] = (float)exp((double)prod);
  }
  if (lane == 0) {
    const int* p32 = (const int*)eidx;
    int is64 = 1;
    for (int i = 1; i < 128; i += 2)
      if (p32[i] != 0) { is64 = 0; break; }
    const u16* q16 = (const u16*)nemb;
    int fbf = 1;
    for (int i = 0; i < 128; i += 2) {
      unsigned e = (q16[i] >> 7) & 0xFF;
      if (e < 90 || e > 140) { fbf = 0; break; }
    }
    flags[0] = is64;
    flags[1] = fbf;
  }
}

__global__ void sentinel_kernel(const int* __restrict__ flags, void* __restrict__ out) {
  int i = blockIdx.x * 256 + threadIdx.x;
  if (i < NE) stout(out, i, 3000.0f, flags[1] != 0);
}
__global__ void raw_sentinel_kernel(u16* __restrict__ out) {
  int i = blockIdx.x * 256 + threadIdx.x;
  if (i < NE) out[i] = f2bf(3000.0f);
}

// ---------------- CSR build ----------------
__global__ void zero_kernel(int* __restrict__ p, int n) {
  int i = blockIdx.x * 256 + threadIdx.x;
  if (i < n) p[i] = 0;
}

__global__ void hist_kernel(const int* __restrict__ flags, const void* __restrict__ eidx,
                            int* __restrict__ cnt) {
  bool is64 = flags[0] != 0;
  int e = blockIdx.x * 256 + threadIdx.x;
  if (e < NE) {
    int d = lddst(eidx, e, is64);
    if ((unsigned)d < NN) atomicAdd(&cnt[d], 1);
  }
}

__global__ void scan1_kernel(const int* __restrict__ cnt, int* __restrict__ offs,
                             int* __restrict__ bsum, int n) {
  __shared__ int s[256];
  int b = blockIdx.x, t = threadIdx.x, i = b * 256 + t;
  int x = (i < n) ? cnt[i] : 0;
  s[t] = x;
  __syncthreads();
  for (int off = 1; off < 256; off <<= 1) {
    int y = (t >= off) ? s[t - off] : 0;
    __syncthreads();
    s[t] += y;
    __syncthreads();
  }
  if (i < n) offs[i] = s[t] - x;
  if (t == 255) bsum[b] = s[t];
}

__global__ void scan2_kernel(int* __restrict__ bsum, int* __restrict__ offs,
                             int nb, int n) {
  __shared__ int s[256];
  int t = threadIdx.x;
  int x = (t < nb) ? bsum[t] : 0;
  s[t] = x;
  __syncthreads();
  for (int off = 1; off < 256; off <<= 1) {
    int y = (t >= off) ? s[t - off] : 0;
    __syncthreads();
    s[t] += y;
    __syncthreads();
  }
  if (t < nb) bsum[t] = s[t] - x;
  if (t == 255) offs[n] = s[t];
}

__global__ void scan3_kernel(int* __restrict__ offs, const int* __restrict__ bsum,
                             int* __restrict__ cursor, int n) {
  int i = blockIdx.x * 256 + threadIdx.x;
  if (i < n) {
    int v = offs[i] + bsum[blockIdx.x];
    offs[i] = v;
    cursor[i] = v;
  }
}

__global__ void fill_kernel(const int* __restrict__ flags, const void* __restrict__ eidx,
                            const void* __restrict__ rawt, const void* __restrict__ noise,
                            int* __restrict__ cursor, int* __restrict__ ssrc,
                            float* __restrict__ stt) {
  bool is64 = flags[0] != 0, fbf = flags[1] != 0;
  int e = blockIdx.x * 256 + threadIdx.x;
  if (e < NE) {
    int d = lddst(eidx, e, is64);
    if ((unsigned)d < NN) {
      int pos = atomicAdd(&cursor[d], 1);
      if ((unsigned)pos < NE) {
        int src = ldsrc(eidx, e, is64);
        if ((unsigned)src >= NN) src = 0;
        ssrc[pos] = src;
        stt[pos] = ldf(rawt, e, fbf) + ldf(noise, e, fbf);
      }
    }
  }
}

// ---------------- A-cast: f32 node_emb -> bf16 (bit-identical to old in-GEMM f2bf) --
__global__ __launch_bounds__(256) void cast_kernel(const int* __restrict__ flags,
                                                   const void* __restrict__ in,
                                                   u16* __restrict__ out) {
  if (flags[1]) return;                       // input already bf16: gemm reads it directly
  int i = blockIdx.x * 256 + threadIdx.x;     // one float4 per thread
  if (i < NN * NIN / 4) {
    float4 v = ((const float4*)in)[i];
    ushort4 o;
    o.x = f2bf(v.x); o.y = f2bf(v.y); o.z = f2bf(v.z); o.w = f2bf(v.w);
    ((ushort4*)out)[i] = o;
  }
}

// ---------------- merged weight transpose: 3 matrices -> WtBig rows 0/256/512 -----
__global__ void transw3_kernel(const int* __restrict__ flags, const void* __restrict__ W0,
                               const void* __restrict__ W1, const void* __restrict__ W2,
                               u16* __restrict__ WtBig, int K) {
  bool fbf = flags[1] != 0;
  __shared__ u16 tile[64][65];
  int z = blockIdx.z;
  const void* W = (z == 0) ? W0 : (z == 1) ? W1 : W2;
  u16* dst = WtBig + (size_t)z * 256 * K;
  int kb = blockIdx.x * 64, cb = blockIdx.y * 64;
  int tx = threadIdx.x & 63, ty = threadIdx.x >> 6;
  for (int i = ty; i < 64; i += 4)
    tile[tx][i] = f2bf(ldf(W, (kb + i) * HC + cb + tx, fbf));
  __syncthreads();
  for (int i = ty; i < 64; i += 4)
    dst[(size_t)(cb + i) * K + kb + tx] = tile[i][tx];
}

// ---------------- wcomb + biasBig merged ----------------
__global__ void wcombbias_kernel(const int* __restrict__ flags, const void* __restrict__ wt,
                                 const u16* __restrict__ Wqt, u16* __restrict__ Wout,
                                 const void* __restrict__ bq, const void* __restrict__ bk,
                                 const void* __restrict__ bv, float* __restrict__ biasBig,
                                 int K) {
  bool fbf = flags[1] != 0;
  int b = blockIdx.x, t = threadIdx.x;
  if (b < 256) {
    __shared__ float wrow[64];
    int j = b, h = j >> 6;
    if (t < 64) wrow[t] = ldf(wt, (j & 63) * HC + h * 64 + t, fbf);
    __syncthreads();
    if (t < K) {
      float s = 0.f;
#pragma unroll 8
      for (int mm = 0; mm < 64; ++mm)
        s += wrow[mm] * bf2f(Wqt[(size_t)(h * 64 + mm) * K + t]);
      Wout[(size_t)j * K + t] = f2bf(s);
    }
  } else if (b < 259) {
    int bb = b - 256;
    const void* p = (bb == 0) ? bq : (bb == 1) ? bk : bv;
    biasBig[bb * 256 + t] = ldf(p, t, fbf);
  } else {
    int j = t, h = j >> 6;
    float s = 0.f;
    for (int mm = 0; mm < 64; ++mm)
      s += ldf(bq, h * 64 + mm, fbf) * ldf(wt, (j & 63) * HC + h * 64 + mm, fbf);
    biasBig[768 + j] = s;
  }
}

// ---------------- fused MFMA GEMM — 128x128 tile, double-buffered ----------------
// v3: XCD-chunked 1D dispatch. lid&7 -> XCD (round-robin heuristic): each XCD
// owns a contiguous ~20-row-tile band of A and iterates its 8 col-tiles
// col-fastest. Per-XCD L2 working set = A band (<=1.3MB) + B (<=0.5MB): A is
// fetched ONCE (old (157,8) grid re-fetched every A row 8x -> FETCH 42MB vs
// ~11 ideal) and staging becomes L2-hit (~200cy) instead of L3 (~900cy),
// feeding the shallow 4-8 step K-loop. A is always bf16 (pre-cast kernel).
template <bool AWS>
__global__ __launch_bounds__(256) void gemm_mfma(
    const int* __restrict__ flags, const void* __restrict__ Ap,
    const u16* __restrict__ Acast, const u16* __restrict__ Wt,
    const float* __restrict__ bias, u16* __restrict__ C, int M, int K) {
  bool fbf = flags[1] != 0;
  const u16* A = AWS ? (const u16*)Ap : (fbf ? (const u16*)Ap : Acast);

  // 1D -> (row-tile, col-tile) with XCD banding; col varies fastest per XCD.
  int lid = blockIdx.x;
  int xcd = lid & 7;
  int j = lid >> 3;                   // 0..159
  int rl = j >> 3, col = j & 7;
  const int qr = GEMM_RT >> 3, rem = GEMM_RT & 7;       // 19, 5
  int nrows = qr + (xcd < rem ? 1 : 0);
  if (rl >= nrows) return;
  int row = xcd * qr + (xcd < rem ? xcd : rem) + rl;
  int rb = row * 128, cb = col * 128;

  __shared__ u16 As[2][128 * 32];
  __shared__ u16 Bs[2][128 * 32];
  int tid = threadIdx.x;
  int wave = tid >> 6, lane = tid & 63;
  int l15 = lane & 15, quad = lane >> 4;
  int mbase = (wave >> 1) * 64, nbase = (wave & 1) * 64;

  f32x4 acc[4][4];
#pragma unroll
  for (int mt = 0; mt < 4; ++mt)
#pragma unroll
    for (int nt = 0; nt < 4; ++nt)
#pragma unroll
      for (int r = 0; r < 4; ++r) acc[mt][nt][r] = 0.f;

  // staging slots: sidx = tid and tid+256; srow = sidx>>2 (0..127), schunk = sidx&3
  int srow0 = tid >> 2, schunk0 = tid & 3;
  int srow1 = (tid + 256) >> 2, schunk1 = (tid + 256) & 3;
  int gchunk0 = schunk0 ^ (srow0 & 3);
  int gchunk1 = schunk1 ^ (srow1 & 3);
  int arow0 = rb + srow0; if (arow0 >= M) arow0 = M - 1;
  int arow1 = rb + srow1; if (arow1 >= M) arow1 = M - 1;
  int slo0 = srow0 * 32 + schunk0 * 8;
  int slo1 = srow1 * 32 + schunk1 * 8;
  const u16* bsrc0 = Wt + (size_t)(cb + srow0) * K + gchunk0 * 8;
  const u16* bsrc1 = Wt + (size_t)(cb + srow1) * K + gchunk1 * 8;
  const u16* asrc0 = A + (size_t)arow0 * K + gchunk0 * 8;
  const u16* asrc1 = A + (size_t)arow1 * K + gchunk1 * 8;

  auto STAGE = [&](int b, int kk) {
    gload_lds16(asrc0 + kk, &As[b][slo0]);
    gload_lds16(asrc1 + kk, &As[b][slo1]);
    gload_lds16(bsrc0 + kk, &Bs[b][slo0]);
    gload_lds16(bsrc1 + kk, &Bs[b][slo1]);
  };

  auto COMPUTE = [&](int b) {
    bf16x8 bfrag[4];
#pragma unroll
    for (int nt = 0; nt < 4; ++nt) {
      int col2 = nbase + nt * 16 + l15;
      bfrag[nt] = *(const bf16x8*)&Bs[b][col2 * 32 + ((quad ^ (col2 & 3)) * 8)];
    }
#pragma unroll
    for (int mt = 0; mt < 4; ++mt) {
      int row2 = mbase + mt * 16 + l15;
      bf16x8 afrag = *(const bf16x8*)&As[b][row2 * 32 + ((quad ^ (row2 & 3)) * 8)];
#pragma unroll
      for (int nt = 0; nt < 4; ++nt)
        acc[mt][nt] = __builtin_amdgcn_mfma_f32_16x16x32_bf16(afrag, bfrag[nt], acc[mt][nt], 0, 0, 0);
    }
  };

  STAGE(0, 0);
  __syncthreads();            // buf0 ready (barrier drains vmcnt)
  int cur = 0;
  for (int kk = 32; kk < K; kk += 32) {
    STAGE(cur ^ 1, kk);       // async loads for next step, in flight under COMPUTE
    COMPUTE(cur);
    __syncthreads();          // next buf ready + everyone done with cur
    cur ^= 1;
  }
  COMPUTE(cur);

  // epilogue: identity scol = gcol; nt-inner order so a row's 4 chunks (128B)
  // are issued back-to-back for line coalescing.
  float bvv[4];
#pragma unroll
  for (int nt = 0; nt < 4; ++nt) bvv[nt] = bias[cb + nbase + nt * 16 + l15];
#pragma unroll
  for (int mt = 0; mt < 4; ++mt) {
#pragma unroll
    for (int r = 0; r < 4; ++r) {
      int grow = rb + mbase + mt * 16 + quad * 4 + r;
      if (grow < M) {
        size_t rowo = (size_t)grow * NB + cb + nbase + l15;
#pragma unroll
        for (int nt = 0; nt < 4; ++nt)
          C[rowo + nt * 16] = f2bf(acc[mt][nt][r] + bvv[nt]);
      }
    }
  }
}

// ---------------- fused alpha + softmax + aggregation + relu -----------------------
// (unchanged from round 4 -- serves as counter control this round)
template <int DOY>
__global__ __launch_bounds__(256) void aggfused_kernel(
    const int* __restrict__ flags, const int* __restrict__ ssrc,
    const int* __restrict__ offsets, const float* __restrict__ stt,
    const float* __restrict__ divt,
    const u16* __restrict__ qkvp, const void* __restrict__ bt,
    u16* __restrict__ xout, const void* __restrict__ wc,
    float* __restrict__ ynode) {
  bool fbf = flags[1] != 0;
  int lane = threadIdx.x & 63;
  int c = lane * 4;

  // node-invariant per-lane data
  int i0 = (2 * lane) & 31;                 // this lane's two time-frequencies
  float dc0 = divt[i0], dc1 = divt[i0 + 1];
  float btv0 = ldf(bt, c + 0, fbf), btv1 = ldf(bt, c + 1, fbf);
  float btv2 = ldf(bt, c + 2, fbf), btv3 = ldf(bt, c + 3, fbf);
  float wcv0 = 0.f, wcv1 = 0.f, wcv2 = 0.f, wcv3 = 0.f;
  if (DOY) {
    wcv0 = ldf(wc, c + 0, fbf); wcv1 = ldf(wc, c + 1, fbf);
    wcv2 = ldf(wc, c + 2, fbf); wcv3 = ldf(wc, c + 3, fbf);
  }

  // first node of this wave; prefetch its data
  int n = blockIdx.x * 4 + (threadIdx.x >> 6);   // 0..9999
  int s0 = offsets[n], s1 = offsets[n + 1];
  int2 q2 = *(const int2*)(qkvp + (size_t)n * NB + c);
  int2 p2 = *(const int2*)(qkvp + (size_t)n * NB + 768 + c);

  while (n < NN) {
    // next node is statically known: issue its loads now, consume next iter
    int n1 = n + AGG_STRIDE;
    int n1c = (n1 < NN) ? n1 : 0;
    int s0n = offsets[n1c], s1n = offsets[n1c + 1];
    int2 q2n = *(const int2*)(qkvp + (size_t)n1c * NB + c);
    int2 p2n = *(const int2*)(qkvp + (size_t)n1c * NB + 768 + c);

    // ---- process node n (data already resident) ----
    float qx = bflo(q2.x), qy = bfhi(q2.x), qz = bflo(q2.y), qw = bfhi(q2.y);
    float px = bflo(p2.x) * LOG2E_8, py = bfhi(p2.x) * LOG2E_8;
    float pz = bflo(p2.y) * LOG2E_8, pw = bfhi(p2.y) * LOG2E_8;
    float pb = qx * btv0 + qy * btv1 + qz * btv2 + qw * btv3;
    float qb = dpp_row_allsum(pb) * LOG2E_8;
    float qsx = qx * LOG2E_8, qsy = qy * LOG2E_8;
    float qsz = qz * LOG2E_8, qsw = qw * LOG2E_8;

    float denom = 0.f, acc0 = 0.f, acc1 = 0.f, acc2 = 0.f, acc3 = 0.f;
    const int* sp = ssrc + s0;
    const float* tp = stt + s0;
    int ecnt = s1 - s0;
    int e = 0;
    if (ecnt >= 4) {
      int sA = sp[0], sB = sp[1], sC = sp[2], sD = sp[3];
      while (e + 4 <= ecnt) {
        const u16* bA = qkvp + ((unsigned)sA << 10) + c;
        const u16* bB = qkvp + ((unsigned)sB << 10) + c;
        const u16* bC = qkvp + ((unsigned)sC << 10) + c;
        const u16* bD = qkvp + ((unsigned)sD << 10) + c;
        int2 kA = *(const int2*)(bA + 256), vA = *(const int2*)(bA + 512);
        int2 kB = *(const int2*)(bB + 256), vB = *(const int2*)(bB + 512);
        int2 kC = *(const int2*)(bC + 256), vC = *(const int2*)(bC + 512);
        int2 kD = *(const int2*)(bD + 256), vD = *(const int2*)(bD + 512);
        float ttA = tp[e], ttB = tp[e + 1], ttC = tp[e + 2], ttD = tp[e + 3];
        int en = e + 4;
        if (en + 4 <= ecnt) {  // prefetch next quad's srcs (breaks src->kv chain)
          sA = sp[en]; sB = sp[en + 1]; sC = sp[en + 2]; sD = sp[en + 3];
        }
        edge_do(kA, vA, ttA, q2, dc0, dc1, qsx, qsy, qsz, qsw, px, py, pz, pw, qb,
                denom, acc0, acc1, acc2, acc3);
        edge_do(kB, vB, ttB, q2, dc0, dc1, qsx, qsy, qsz, qsw, px, py, pz, pw, qb,
                denom, acc0, acc1, acc2, acc3);
        edge_do(kC, vC, ttC, q2, dc0, dc1, qsx, qsy, qsz, qsw, px, py, pz, pw, qb,
                denom, acc0, acc1, acc2, acc3);
        edge_do(kD, vD, ttD, q2, dc0, dc1, qsx, qsy, qsz, qsw, px, py, pz, pw, qb,
                denom, acc0, acc1, acc2, acc3);
        e = en;
      }
    }
    for (; e < ecnt; ++e) {
      int s = sp[e];
      const u16* bS = qkvp + ((unsigned)s << 10) + c;
      int2 kS = *(const int2*)(bS + 256), vS = *(const int2*)(bS + 512);
      float tt = tp[e];
      edge_do(kS, vS, tt, q2, dc0, dc1, qsx, qsy, qsz, qsw, px, py, pz, pw, qb,
              denom, acc0, acc1, acc2, acc3);
    }

    float inv = 1.f / (denom + 1e-16f);
    ushort4 r;
    r.x = f2bf(fmaxf(acc0 * inv, 0.f));
    r.y = f2bf(fmaxf(acc1 * inv, 0.f));
    r.z = f2bf(fmaxf(acc2 * inv, 0.f));
    r.w = f2bf(fmaxf(acc3 * inv, 0.f));
    *(ushort4*)(xout + (size_t)n * HC + c) = r;
    if (DOY) {
      float yv = bf2f(r.x) * wcv0 + bf2f(r.y) * wcv1 +
                 bf2f(r.z) * wcv2 + bf2f(r.w) * wcv3;
      yv = dpp_row_allsum(yv);
      yv += __shfl_xor(yv, 16);
      yv += __shfl_xor(yv, 32);
      if (lane == 0) ynode[n] = yv;
    }

    // rotate pipeline
    n = n1;
    s0 = s0n; s1 = s1n; q2 = q2n; p2 = p2n;
  }
}

// ---------------- out[e] = y[src] + y[dst] + bc ----------------
__global__ __launch_bounds__(256) void final2_kernel(
    const int* __restrict__ flags, const void* __restrict__ eidx,
    const float* __restrict__ y, const void* __restrict__ bc,
    void* __restrict__ out) {
  bool is64 = flags[0] != 0, fbf = flags[1] != 0;
  int e = blockIdx.x * 256 + threadIdx.x;
  if (e >= NE) return;
  int src = ldsrc(eidx, e, is64);
  int dst = lddst(eidx, e, is64);
  if ((unsigned)src >= NN) src = 0;
  if ((unsigned)dst >= NN) dst = 0;
  stout(out, e, y[src] + y[dst] + ldf(bc, 0, fbf), fbf);
}

extern "C" void kernel_launch(void* const* d_in, const int* in_sizes, int n_in,
                              void* d_out, int out_size, void* d_ws, size_t ws_size,
                              hipStream_t stream) {
  const void* eidx  = d_in[0];
  const void* rawt  = d_in[1];
  const void* noise = d_in[2];
  const void* nemb  = d_in[3];
  const void *wq1 = d_in[4],  *bq1 = d_in[5];
  const void *wk1 = d_in[6],  *bk1 = d_in[7];
  const void *wv1 = d_in[8],  *bv1 = d_in[9];
  const void *wt1 = d_in[10], *bt1 = d_in[11];
  const void *wq2 = d_in[12], *bq2 = d_in[13];
  const void *wk2 = d_in[14], *bk2 = d_in[15];
  const void *wv2 = d_in[16], *bv2 = d_in[17];
  const void *wt2 = d_in[18], *bt2 = d_in[19];
  const void *wcp = d_in[20], *bcp = d_in[21];

  char* ws = (char*)d_ws;
  size_t off = 0;
  auto alloc = [&](size_t bytes) -> void* {
    void* p = ws + off;
    off += (bytes + 255) & ~(size_t)255;
    return p;
  };
  int*   flags  = (int*)alloc(256);
  float* divt   = (float*)alloc(256);
  u16*   WtBig  = (u16*)alloc((size_t)NB * HC * 2);
  float* biasBig= (float*)alloc((size_t)NB * 4);
  u16*   qkvp   = (u16*)alloc((size_t)NN * NB * 2);
  u16*   x1     = (u16*)alloc((size_t)NN * HC * 2);
  u16*   x2     = (u16*)alloc((size_t)NN * HC * 2);
  u16*   acast  = (u16*)alloc((size_t)NN * NIN * 2);
  float* ynode  = (float*)alloc((size_t)NN * 4);
  int* offsets  = (int*)alloc((size_t)(NN + 1) * 4);
  int* cursor   = (int*)alloc((size_t)NN * 4);
  int* bsum     = (int*)alloc(256 * 4);
  int* ssrc     = (int*)alloc((size_t)NE * 4);
  float* stt    = (float*)alloc((size_t)NE * 4);
  size_t need = off;

  int gN = (NN + 255) / 256, gE = (NE + 255) / 256;
  int nb = (NN + 255) / 256;

  if (ws_size < 1024) {
    raw_sentinel_kernel<<<gE, 256, 0, stream>>>((u16*)d_out);
    return;
  }
  devinit_kernel<<<1, 64, 0, stream>>>(eidx, nemb, flags, divt);
  if (need > ws_size) {
    sentinel_kernel<<<gE, 256, 0, stream>>>(flags, d_out);
    return;
  }

  // CSR by dst (+ sorted src / time)
  zero_kernel<<<gN, 256, 0, stream>>>(cursor, NN);
  hist_kernel<<<gE, 256, 0, stream>>>(flags, eidx, cursor);
  scan1_kernel<<<nb, 256, 0, stream>>>(cursor, offsets, bsum, NN);
  scan2_kernel<<<1, 256, 0, stream>>>(bsum, offsets, nb, NN);
  scan3_kernel<<<nb, 256, 0, stream>>>(offsets, bsum, cursor, NN);
  fill_kernel<<<gE, 256, 0, stream>>>(flags, eidx, rawt, noise, cursor, ssrc, stt);

  // A-cast for layer 1 (no-op if input already bf16)
  cast_kernel<<<(NN * NIN / 4 + 255) / 256, 256, 0, stream>>>(flags, nemb, acast);

  dim3 gt1(NIN / 64, 4, 3), gt2(HC / 64, 4, 3);

  // ---- Layer 1 (A = node_emb bf16, K=128) ----
  transw3_kernel<<<gt1, 256, 0, stream>>>(flags, wq1, wk1, wv1, WtBig, NIN);
  wcombbias_kernel<<<260, 256, 0, stream>>>(flags, wt1, WtBig, WtBig + (size_t)768 * NIN,
                                            bq1, bk1, bv1, biasBig, NIN);
  gemm_mfma<false><<<GEMM_BLOCKS, 256, 0, stream>>>(flags, nemb, acast, WtBig, biasBig,
                                                    qkvp, NN, NIN);
  aggfused_kernel<0><<<AGG_BLOCKS, 256, 0, stream>>>(flags, ssrc, offsets, stt, divt,
                                                     qkvp, bt1, x1, wcp, ynode);

  // ---- Layer 2 (A = bf16 x1, K=256) ----
  transw3_kernel<<<gt2, 256, 0, stream>>>(flags, wq2, wk2, wv2, WtBig, HC);
  wcombbias_kernel<<<260, 256, 0, stream>>>(flags, wt2, WtBig, WtBig + (size_t)768 * HC,
                                            bq2, bk2, bv2, biasBig, HC);
  gemm_mfma<true><<<GEMM_BLOCKS, 256, 0, stream>>>(flags, x1, (const u16*)0, WtBig, biasBig,
                                                   qkvp, NN, HC);
  aggfused_kernel<1><<<AGG_BLOCKS, 256, 0, stream>>>(flags, ssrc, offsets, stt, divt,
                                                     qkvp, bt2, x2, wcp, ynode);

  // Edge scorer epilogue
  final2_kernel<<<gE, 256, 0, stream>>>(flags, eidx, ynode, bcp, d_out);
}

// Round 6
// 324.943 us; speedup vs baseline: 2.9432x; 1.0007x over previous
//
#include <hip/hip_runtime.h>
#include <hip/hip_fp16.h>
#include <math.h>

// Problem constants
#define NN   20000     // nodes
#define NE   320000    // edges
#define NIN  128       // node input dim
#define HC   256       // heads(4) * hidden(64)
#define NB   1024      // fused GEMM output width: [q | k | v | qproj] (identity layout)

// aggfused work distribution: 2500 blocks x 4 waves = 10000 waves, 2 strided
// nodes each (static, no atomics).
#define AGG_BLOCKS 2500
#define AGG_STRIDE 10000
#define LOG2E_8    0.18033688f   // log2(e)/8 -- folds the 1/sqrt(64) scale + exp->exp2

// gemm grid: 8 XCD chunks x 20 row-slots x 8 col-tiles = 1280 blocks (1D)
#define GEMM_BLOCKS 1280
#define GEMM_RT     157        // row tiles = ceil(20000/128)

typedef unsigned short u16;
typedef __attribute__((ext_vector_type(8))) short bf16x8;
typedef __attribute__((ext_vector_type(4))) float f32x4;

__device__ __forceinline__ float bf2f(u16 u) {
  union { unsigned int i; float f; } x;
  x.i = ((unsigned int)u) << 16;
  return x.f;
}
__device__ __forceinline__ u16 f2bf(float f) {
  union { float f; unsigned int i; } x;
  x.f = f;
  unsigned int r = x.i + 0x7fffu + ((x.i >> 16) & 1u);
  return (u16)(r >> 16);
}
// packed-pair bf16 unpack: lo = <<16, hi = mask (1 VALU op each)
__device__ __forceinline__ float bflo(int v) {
  union { int i; float f; } x; x.i = v << 16; return x.f;
}
__device__ __forceinline__ float bfhi(int v) {
  union { int i; float f; } x; x.i = v & 0xffff0000; return x.f;
}

// dtype-flexible loads (flags detected on device each launch)
__device__ __forceinline__ float ldf(const void* p, int i, bool fbf) {
  return fbf ? bf2f(((const u16*)p)[i]) : ((const float*)p)[i];
}
__device__ __forceinline__ int ldsrc(const void* p, int e, bool is64) {
  const int* p32 = (const int*)p;
  return is64 ? p32[2 * e] : p32[e];
}
__device__ __forceinline__ int lddst(const void* p, int e, bool is64) {
  const int* p32 = (const int*)p;
  return is64 ? p32[2 * (NE + e)] : p32[NE + e];
}
__device__ __forceinline__ void stout(void* p, int i, float v, bool fbf) {
  if (fbf) ((u16*)p)[i] = f2bf(v);
  else ((float*)p)[i] = v;
}

// async global->LDS, 16B per lane
__device__ __forceinline__ void gload_lds16(const u16* g, u16* l) {
  __builtin_amdgcn_global_load_lds(
      (const __attribute__((address_space(1))) void*)g,
      (__attribute__((address_space(3))) void*)l, 16, 0, 0);
}

// 16-lane (row) all-sum via DPP row_ror adds: pure VALU, replaces 4 ds_bpermute.
__device__ __forceinline__ float dpp_row_allsum(float s) {
  union fi { float f; int i; };
  fi a, b;
  a.f = s;
  b.i = __builtin_amdgcn_update_dpp(0, a.i, 0x121, 0xf, 0xf, true); a.f += b.f;
  b.i = __builtin_amdgcn_update_dpp(0, a.i, 0x122, 0xf, 0xf, true); a.f += b.f;
  b.i = __builtin_amdgcn_update_dpp(0, a.i, 0x124, 0xf, 0xf, true); a.f += b.f;
  b.i = __builtin_amdgcn_update_dpp(0, a.i, 0x128, 0xf, 0xf, true); a.f += b.f;
  return a.f;
}

__device__ __forceinline__ float fexp2(float x) {
#if __has_builtin(__builtin_amdgcn_exp2f)
  return __builtin_amdgcn_exp2f(x);
#else
  return exp2f(x);
#endif
}

#if __has_builtin(__builtin_amdgcn_fdot2_f32_bf16)
#define HAS_BF16_DOT2 1
typedef __attribute__((ext_vector_type(2))) __bf16 bfv2_t;
__device__ __forceinline__ float qkdot2(int a, int b, float c) {
  return __builtin_amdgcn_fdot2_f32_bf16(__builtin_bit_cast(bfv2_t, a),
                                         __builtin_bit_cast(bfv2_t, b), c, false);
}
#else
#define HAS_BF16_DOT2 0
#endif

// one edge: inline time-encode (exact f32 Cody-Waite 1/2pi reduction of the
// f32 product arg = fl(tt*divt), matching the reference's sin(f32 arg)), then
// alpha partial -> DPP row reduce -> exp2 -> accumulate. No max tracking
// (|alpha| <= ~3 by construction, f32 exp2 safe by a huge margin).
__device__ __forceinline__ void edge_do(int2 kk, int2 vv, float tt, int2 q2,
    float dc0, float dc1,
    float qsx, float qsy, float qsz, float qsw,
    float px, float py, float pz, float pw, float qb,
    float& denom, float& a0, float& a1, float& a2, float& a3) {
  const float CH = 0.15915494f;                                    // f32(1/2pi)
  const float CL = (float)(0.15915494309189535 - (double)0.15915494f);
  float x0 = tt * dc0, x1 = tt * dc1;     // = reference's f32 arg
  float p0 = x0 * CH, p1 = x1 * CH;
  float e0 = fmaf(x0, CH, -p0), e1 = fmaf(x1, CH, -p1);
  e0 = fmaf(x0, CL, e0);  e1 = fmaf(x1, CL, e1);
  float fr0 = (p0 - rintf(p0)) + e0;      // revolutions, |fr| <= ~0.5
  float fr1 = (p1 - rintf(p1)) + e1;
  float sv0 = __builtin_amdgcn_sinf(fr0), cv0 = __builtin_amdgcn_cosf(fr0);
  float sv1 = __builtin_amdgcn_sinf(fr1), cv1 = __builtin_amdgcn_cosf(fr1);
  float stp = sv0 * px + cv0 * py + sv1 * pz + cv1 * pw;
#if HAS_BF16_DOT2
  float sqk = qkdot2(kk.y, q2.y, qkdot2(kk.x, q2.x, 0.f));
  float partial = sqk * LOG2E_8 + stp;
#else
  float partial = stp + qsx * bflo(kk.x) + qsy * bfhi(kk.x) +
                  qsz * bflo(kk.y) + qsw * bfhi(kk.y);
#endif
  float a = dpp_row_allsum(partial) + qb;
  float ea = fexp2(a);
  denom += ea;
  a0 = fmaf(ea, bflo(vv.x), a0);
  a1 = fmaf(ea, bfhi(vv.x), a1);
  a2 = fmaf(ea, bflo(vv.y), a2);
  a3 = fmaf(ea, bfhi(vv.y), a3);
}

// ---------------- detection + div_term init ----------------
__global__ void devinit_kernel(const void* __restrict__ eidx,
                               const void* __restrict__ nemb,
                               int* __restrict__ flags, float* __restrict__ divt) {
  int lane = threadIdx.x;
  if (lane < 32) {
    const float c32 = (float)(-0.14391156831212787);
    float prod = (float)(2 * lane) * c32;
    divt[lane] = (float)exp((double)prod);
  }
  if (lane == 0) {
    const int* p32 = (const int*)eidx;
    int is64 = 1;
    for (int i = 1; i < 128; i += 2)
      if (p32[i] != 0) { is64 = 0; break; }
    const u16* q16 = (const u16*)nemb;
    int fbf = 1;
    for (int i = 0; i < 128; i += 2) {
      unsigned e = (q16[i] >> 7) & 0xFF;
      if (e < 90 || e > 140) { fbf = 0; break; }
    }
    flags[0] = is64;
    flags[1] = fbf;
  }
}

__global__ void sentinel_kernel(const int* __restrict__ flags, void* __restrict__ out) {
  int i = blockIdx.x * 256 + threadIdx.x;
  if (i < NE) stout(out, i, 3000.0f, flags[1] != 0);
}
__global__ void raw_sentinel_kernel(u16* __restrict__ out) {
  int i = blockIdx.x * 256 + threadIdx.x;
  if (i < NE) out[i] = f2bf(3000.0f);
}

// ---------------- CSR build ----------------
__global__ void zero_kernel(int* __restrict__ p, int n) {
  int i = blockIdx.x * 256 + threadIdx.x;
  if (i < n) p[i] = 0;
}

__global__ void hist_kernel(const int* __restrict__ flags, const void* __restrict__ eidx,
                            int* __restrict__ cnt) {
  bool is64 = flags[0] != 0;
  int e = blockIdx.x * 256 + threadIdx.x;
  if (e < NE) {
    int d = lddst(eidx, e, is64);
    if ((unsigned)d < NN) atomicAdd(&cnt[d], 1);
  }
}

__global__ void scan1_kernel(const int* __restrict__ cnt, int* __restrict__ offs,
                             int* __restrict__ bsum, int n) {
  __shared__ int s[256];
  int b = blockIdx.x, t = threadIdx.x, i = b * 256 + t;
  int x = (i < n) ? cnt[i] : 0;
  s[t] = x;
  __syncthreads();
  for (int off = 1; off < 256; off <<= 1) {
    int y = (t >= off) ? s[t - off] : 0;
    __syncthreads();
    s[t] += y;
    __syncthreads();
  }
  if (i < n) offs[i] = s[t] - x;
  if (t == 255) bsum[b] = s[t];
}

__global__ void scan2_kernel(int* __restrict__ bsum, int* __restrict__ offs,
                             int nb, int n) {
  __shared__ int s[256];
  int t = threadIdx.x;
  int x = (t < nb) ? bsum[t] : 0;
  s[t] = x;
  __syncthreads();
  for (int off = 1; off < 256; off <<= 1) {
    int y = (t >= off) ? s[t - off] : 0;
    __syncthreads();
    s[t] += y;
    __syncthreads();
  }
  if (t < nb) bsum[t] = s[t] - x;
  if (t == 255) offs[n] = s[t];
}

__global__ void scan3_kernel(int* __restrict__ offs, const int* __restrict__ bsum,
                             int* __restrict__ cursor, int n) {
  int i = blockIdx.x * 256 + threadIdx.x;
  if (i < n) {
    int v = offs[i] + bsum[blockIdx.x];
    offs[i] = v;
    cursor[i] = v;
  }
}

__global__ void fill_kernel(const int* __restrict__ flags, const void* __restrict__ eidx,
                            const void* __restrict__ rawt, const void* __restrict__ noise,
                            int* __restrict__ cursor, int* __restrict__ ssrc,
                            float* __restrict__ stt) {
  bool is64 = flags[0] != 0, fbf = flags[1] != 0;
  int e = blockIdx.x * 256 + threadIdx.x;
  if (e < NE) {
    int d = lddst(eidx, e, is64);
    if ((unsigned)d < NN) {
      int pos = atomicAdd(&cursor[d], 1);
      if ((unsigned)pos < NE) {
        int src = ldsrc(eidx, e, is64);
        if ((unsigned)src >= NN) src = 0;
        ssrc[pos] = src;
        stt[pos] = ldf(rawt, e, fbf) + ldf(noise, e, fbf);
      }
    }
  }
}

// ---------------- A-cast: f32 node_emb -> bf16 (bit-identical to old in-GEMM f2bf) --
__global__ __launch_bounds__(256) void cast_kernel(const int* __restrict__ flags,
                                                   const void* __restrict__ in,
                                                   u16* __restrict__ out) {
  if (flags[1]) return;                       // input already bf16: gemm reads it directly
  int i = blockIdx.x * 256 + threadIdx.x;     // one float4 per thread
  if (i < NN * NIN / 4) {
    float4 v = ((const float4*)in)[i];
    ushort4 o;
    o.x = f2bf(v.x); o.y = f2bf(v.y); o.z = f2bf(v.z); o.w = f2bf(v.w);
    ((ushort4*)out)[i] = o;
  }
}

// ---------------- merged weight transpose: 3 matrices -> WtBig rows 0/256/512 -----
__global__ void transw3_kernel(const int* __restrict__ flags, const void* __restrict__ W0,
                               const void* __restrict__ W1, const void* __restrict__ W2,
                               u16* __restrict__ WtBig, int K) {
  bool fbf = flags[1] != 0;
  __shared__ u16 tile[64][65];
  int z = blockIdx.z;
  const void* W = (z == 0) ? W0 : (z == 1) ? W1 : W2;
  u16* dst = WtBig + (size_t)z * 256 * K;
  int kb = blockIdx.x * 64, cb = blockIdx.y * 64;
  int tx = threadIdx.x & 63, ty = threadIdx.x >> 6;
  for (int i = ty; i < 64; i += 4)
    tile[tx][i] = f2bf(ldf(W, (kb + i) * HC + cb + tx, fbf));
  __syncthreads();
  for (int i = ty; i < 64; i += 4)
    dst[(size_t)(cb + i) * K + kb + tx] = tile[i][tx];
}

// ---------------- wcomb + biasBig merged ----------------
__global__ void wcombbias_kernel(const int* __restrict__ flags, const void* __restrict__ wt,
                                 const u16* __restrict__ Wqt, u16* __restrict__ Wout,
                                 const void* __restrict__ bq, const void* __restrict__ bk,
                                 const void* __restrict__ bv, float* __restrict__ biasBig,
                                 int K) {
  bool fbf = flags[1] != 0;
  int b = blockIdx.x, t = threadIdx.x;
  if (b < 256) {
    __shared__ float wrow[64];
    int j = b, h = j >> 6;
    if (t < 64) wrow[t] = ldf(wt, (j & 63) * HC + h * 64 + t, fbf);
    __syncthreads();
    if (t < K) {
      float s = 0.f;
#pragma unroll 8
      for (int mm = 0; mm < 64; ++mm)
        s += wrow[mm] * bf2f(Wqt[(size_t)(h * 64 + mm) * K + t]);
      Wout[(size_t)j * K + t] = f2bf(s);
    }
  } else if (b < 259) {
    int bb = b - 256;
    const void* p = (bb == 0) ? bq : (bb == 1) ? bk : bv;
    biasBig[bb * 256 + t] = ldf(p, t, fbf);
  } else {
    int j = t, h = j >> 6;
    float s = 0.f;
    for (int mm = 0; mm < 64; ++mm)
      s += ldf(bq, h * 64 + mm, fbf) * ldf(wt, (j & 63) * HC + h * 64 + mm, fbf);
    biasBig[768 + j] = s;
  }
}

// ---------------- fused MFMA GEMM — 128x128 tile, double-buffered ----------------
// (unchanged from round 5 -- XCD-chunked dispatch, identity layout, 2-phase dbuf)
template <bool AWS>
__global__ __launch_bounds__(256) void gemm_mfma(
    const int* __restrict__ flags, const void* __restrict__ Ap,
    const u16* __restrict__ Acast, const u16* __restrict__ Wt,
    const float* __restrict__ bias, u16* __restrict__ C, int M, int K) {
  bool fbf = flags[1] != 0;
  const u16* A = AWS ? (const u16*)Ap : (fbf ? (const u16*)Ap : Acast);

  // 1D -> (row-tile, col-tile) with XCD banding; col varies fastest per XCD.
  int lid = blockIdx.x;
  int xcd = lid & 7;
  int j = lid >> 3;                   // 0..159
  int rl = j >> 3, col = j & 7;
  const int qr = GEMM_RT >> 3, rem = GEMM_RT & 7;       // 19, 5
  int nrows = qr + (xcd < rem ? 1 : 0);
  if (rl >= nrows) return;
  int row = xcd * qr + (xcd < rem ? xcd : rem) + rl;
  int rb = row * 128, cb = col * 128;

  __shared__ u16 As[2][128 * 32];
  __shared__ u16 Bs[2][128 * 32];
  int tid = threadIdx.x;
  int wave = tid >> 6, lane = tid & 63;
  int l15 = lane & 15, quad = lane >> 4;
  int mbase = (wave >> 1) * 64, nbase = (wave & 1) * 64;

  f32x4 acc[4][4];
#pragma unroll
  for (int mt = 0; mt < 4; ++mt)
#pragma unroll
    for (int nt = 0; nt < 4; ++nt)
#pragma unroll
      for (int r = 0; r < 4; ++r) acc[mt][nt][r] = 0.f;

  // staging slots: sidx = tid and tid+256; srow = sidx>>2 (0..127), schunk = sidx&3
  int srow0 = tid >> 2, schunk0 = tid & 3;
  int srow1 = (tid + 256) >> 2, schunk1 = (tid + 256) & 3;
  int gchunk0 = schunk0 ^ (srow0 & 3);
  int gchunk1 = schunk1 ^ (srow1 & 3);
  int arow0 = rb + srow0; if (arow0 >= M) arow0 = M - 1;
  int arow1 = rb + srow1; if (arow1 >= M) arow1 = M - 1;
  int slo0 = srow0 * 32 + schunk0 * 8;
  int slo1 = srow1 * 32 + schunk1 * 8;
  const u16* bsrc0 = Wt + (size_t)(cb + srow0) * K + gchunk0 * 8;
  const u16* bsrc1 = Wt + (size_t)(cb + srow1) * K + gchunk1 * 8;
  const u16* asrc0 = A + (size_t)arow0 * K + gchunk0 * 8;
  const u16* asrc1 = A + (size_t)arow1 * K + gchunk1 * 8;

  auto STAGE = [&](int b, int kk) {
    gload_lds16(asrc0 + kk, &As[b][slo0]);
    gload_lds16(asrc1 + kk, &As[b][slo1]);
    gload_lds16(bsrc0 + kk, &Bs[b][slo0]);
    gload_lds16(bsrc1 + kk, &Bs[b][slo1]);
  };

  auto COMPUTE = [&](int b) {
    bf16x8 bfrag[4];
#pragma unroll
    for (int nt = 0; nt < 4; ++nt) {
      int col2 = nbase + nt * 16 + l15;
      bfrag[nt] = *(const bf16x8*)&Bs[b][col2 * 32 + ((quad ^ (col2 & 3)) * 8)];
    }
#pragma unroll
    for (int mt = 0; mt < 4; ++mt) {
      int row2 = mbase + mt * 16 + l15;
      bf16x8 afrag = *(const bf16x8*)&As[b][row2 * 32 + ((quad ^ (row2 & 3)) * 8)];
#pragma unroll
      for (int nt = 0; nt < 4; ++nt)
        acc[mt][nt] = __builtin_amdgcn_mfma_f32_16x16x32_bf16(afrag, bfrag[nt], acc[mt][nt], 0, 0, 0);
    }
  };

  STAGE(0, 0);
  __syncthreads();            // buf0 ready (barrier drains vmcnt)
  int cur = 0;
  for (int kk = 32; kk < K; kk += 32) {
    STAGE(cur ^ 1, kk);       // async loads for next step, in flight under COMPUTE
    COMPUTE(cur);
    __syncthreads();          // next buf ready + everyone done with cur
    cur ^= 1;
  }
  COMPUTE(cur);

  // epilogue: identity scol = gcol; nt-inner order so a row's 4 chunks (128B)
  // are issued back-to-back for line coalescing.
  float bvv[4];
#pragma unroll
  for (int nt = 0; nt < 4; ++nt) bvv[nt] = bias[cb + nbase + nt * 16 + l15];
#pragma unroll
  for (int mt = 0; mt < 4; ++mt) {
#pragma unroll
    for (int r = 0; r < 4; ++r) {
      int grow = rb + mbase + mt * 16 + quad * 4 + r;
      if (grow < M) {
        size_t rowo = (size_t)grow * NB + cb + nbase + l15;
#pragma unroll
        for (int nt = 0; nt < 4; ++nt)
          C[rowo + nt * 16] = f2bf(acc[mt][nt][r] + bvv[nt]);
      }
    }
  }
}

// ---------------- fused alpha + softmax + aggregation + relu -----------------------
// v6: 8-edge software-pipelined groups (16 gathers in flight per wave, 2x the
// round-5 MLP; Little's-law showed ~100 lines in flight vs ~120 needed).
// Group-ahead src prefetch; tt loads are wave-uniform (s_load, no VGPR cost).
template <int DOY>
__global__ __launch_bounds__(256) void aggfused_kernel(
    const int* __restrict__ flags, const int* __restrict__ ssrc,
    const int* __restrict__ offsets, const float* __restrict__ stt,
    const float* __restrict__ divt,
    const u16* __restrict__ qkvp, const void* __restrict__ bt,
    u16* __restrict__ xout, const void* __restrict__ wc,
    float* __restrict__ ynode) {
  bool fbf = flags[1] != 0;
  int lane = threadIdx.x & 63;
  int c = lane * 4;

  // node-invariant per-lane data
  int i0 = (2 * lane) & 31;                 // this lane's two time-frequencies
  float dc0 = divt[i0], dc1 = divt[i0 + 1];
  float btv0 = ldf(bt, c + 0, fbf), btv1 = ldf(bt, c + 1, fbf);
  float btv2 = ldf(bt, c + 2, fbf), btv3 = ldf(bt, c + 3, fbf);
  float wcv0 = 0.f, wcv1 = 0.f, wcv2 = 0.f, wcv3 = 0.f;
  if (DOY) {
    wcv0 = ldf(wc, c + 0, fbf); wcv1 = ldf(wc, c + 1, fbf);
    wcv2 = ldf(wc, c + 2, fbf); wcv3 = ldf(wc, c + 3, fbf);
  }

  // first node of this wave; prefetch its data
  int n = blockIdx.x * 4 + (threadIdx.x >> 6);   // 0..9999
  int s0 = offsets[n], s1 = offsets[n + 1];
  int2 q2 = *(const int2*)(qkvp + (size_t)n * NB + c);
  int2 p2 = *(const int2*)(qkvp + (size_t)n * NB + 768 + c);

  while (n < NN) {
    // next node is statically known: issue its loads now, consume next iter
    int n1 = n + AGG_STRIDE;
    int n1c = (n1 < NN) ? n1 : 0;
    int s0n = offsets[n1c], s1n = offsets[n1c + 1];
    int2 q2n = *(const int2*)(qkvp + (size_t)n1c * NB + c);
    int2 p2n = *(const int2*)(qkvp + (size_t)n1c * NB + 768 + c);

    // ---- process node n (data already resident) ----
    float qx = bflo(q2.x), qy = bfhi(q2.x), qz = bflo(q2.y), qw = bfhi(q2.y);
    float px = bflo(p2.x) * LOG2E_8, py = bfhi(p2.x) * LOG2E_8;
    float pz = bflo(p2.y) * LOG2E_8, pw = bfhi(p2.y) * LOG2E_8;
    float pb = qx * btv0 + qy * btv1 + qz * btv2 + qw * btv3;
    float qb = dpp_row_allsum(pb) * LOG2E_8;
    float qsx = qx * LOG2E_8, qsy = qy * LOG2E_8;
    float qsz = qz * LOG2E_8, qsw = qw * LOG2E_8;

    float denom = 0.f, acc0 = 0.f, acc1 = 0.f, acc2 = 0.f, acc3 = 0.f;
    const int* sp = ssrc + s0;
    const float* tp = stt + s0;
    int ecnt = s1 - s0;
    int e = 0;
    // ---- 8-edge pipelined groups ----
    if (ecnt >= 8) {
      int s[8];
#pragma unroll
      for (int i = 0; i < 8; ++i) s[i] = sp[i];
      while (e + 8 <= ecnt) {
        int2 kk[8], vv[8];
#pragma unroll
        for (int i = 0; i < 8; ++i) {
          const u16* b = qkvp + ((unsigned)s[i] << 10) + c;
          kk[i] = *(const int2*)(b + 256);
          vv[i] = *(const int2*)(b + 512);
        }
        float tt[8];
#pragma unroll
        for (int i = 0; i < 8; ++i) tt[i] = tp[e + i];
        int en = e + 8;
        if (en + 8 <= ecnt) {   // prefetch next group's srcs (breaks src->kv chain)
#pragma unroll
          for (int i = 0; i < 8; ++i) s[i] = sp[en + i];
        }
#pragma unroll
        for (int i = 0; i < 8; ++i)
          edge_do(kk[i], vv[i], tt[i], q2, dc0, dc1, qsx, qsy, qsz, qsw,
                  px, py, pz, pw, qb, denom, acc0, acc1, acc2, acc3);
        e = en;
      }
    }
    // ---- 4-edge remainder group ----
    for (; e + 4 <= ecnt; e += 4) {
      int sA = sp[e], sB = sp[e + 1], sC = sp[e + 2], sD = sp[e + 3];
      const u16* bA = qkvp + ((unsigned)sA << 10) + c;
      const u16* bB = qkvp + ((unsigned)sB << 10) + c;
      const u16* bC = qkvp + ((unsigned)sC << 10) + c;
      const u16* bD = qkvp + ((unsigned)sD << 10) + c;
      int2 kA = *(const int2*)(bA + 256), vA = *(const int2*)(bA + 512);
      int2 kB = *(const int2*)(bB + 256), vB = *(const int2*)(bB + 512);
      int2 kC = *(const int2*)(bC + 256), vC = *(const int2*)(bC + 512);
      int2 kD = *(const int2*)(bD + 256), vD = *(const int2*)(bD + 512);
      float ttA = tp[e], ttB = tp[e + 1], ttC = tp[e + 2], ttD = tp[e + 3];
      edge_do(kA, vA, ttA, q2, dc0, dc1, qsx, qsy, qsz, qsw, px, py, pz, pw, qb,
              denom, acc0, acc1, acc2, acc3);
      edge_do(kB, vB, ttB, q2, dc0, dc1, qsx, qsy, qsz, qsw, px, py, pz, pw, qb,
              denom, acc0, acc1, acc2, acc3);
      edge_do(kC, vC, ttC, q2, dc0, dc1, qsx, qsy, qsz, qsw, px, py, pz, pw, qb,
              denom, acc0, acc1, acc2, acc3);
      edge_do(kD, vD, ttD, q2, dc0, dc1, qsx, qsy, qsz, qsw, px, py, pz, pw, qb,
              denom, acc0, acc1, acc2, acc3);
    }
    for (; e < ecnt; ++e) {
      int s = sp[e];
      const u16* bS = qkvp + ((unsigned)s << 10) + c;
      int2 kS = *(const int2*)(bS + 256), vS = *(const int2*)(bS + 512);
      float tt = tp[e];
      edge_do(kS, vS, tt, q2, dc0, dc1, qsx, qsy, qsz, qsw, px, py, pz, pw, qb,
              denom, acc0, acc1, acc2, acc3);
    }

    float inv = 1.f / (denom + 1e-16f);
    ushort4 r;
    r.x = f2bf(fmaxf(acc0 * inv, 0.f));
    r.y = f2bf(fmaxf(acc1 * inv, 0.f));
    r.z = f2bf(fmaxf(acc2 * inv, 0.f));
    r.w = f2bf(fmaxf(acc3 * inv, 0.f));
    *(ushort4*)(xout + (size_t)n * HC + c) = r;
    if (DOY) {
      float yv = bf2f(r.x) * wcv0 + bf2f(r.y) * wcv1 +
                 bf2f(r.z) * wcv2 + bf2f(r.w) * wcv3;
      yv = dpp_row_allsum(yv);
      yv += __shfl_xor(yv, 16);
      yv += __shfl_xor(yv, 32);
      if (lane == 0) ynode[n] = yv;
    }

    // rotate pipeline
    n = n1;
    s0 = s0n; s1 = s1n; q2 = q2n; p2 = p2n;
  }
}

// ---------------- out[e] = y[src] + y[dst] + bc ----------------
__global__ __launch_bounds__(256) void final2_kernel(
    const int* __restrict__ flags, const void* __restrict__ eidx,
    const float* __restrict__ y, const void* __restrict__ bc,
    void* __restrict__ out) {
  bool is64 = flags[0] != 0, fbf = flags[1] != 0;
  int e = blockIdx.x * 256 + threadIdx.x;
  if (e >= NE) return;
  int src = ldsrc(eidx, e, is64);
  int dst = lddst(eidx, e, is64);
  if ((unsigned)src >= NN) src = 0;
  if ((unsigned)dst >= NN) dst = 0;
  stout(out, e, y[src] + y[dst] + ldf(bc, 0, fbf), fbf);
}

extern "C" void kernel_launch(void* const* d_in, const int* in_sizes, int n_in,
                              void* d_out, int out_size, void* d_ws, size_t ws_size,
                              hipStream_t stream) {
  const void* eidx  = d_in[0];
  const void* rawt  = d_in[1];
  const void* noise = d_in[2];
  const void* nemb  = d_in[3];
  const void *wq1 = d_in[4],  *bq1 = d_in[5];
  const void *wk1 = d_in[6],  *bk1 = d_in[7];
  const void *wv1 = d_in[8],  *bv1 = d_in[9];
  const void *wt1 = d_in[10], *bt1 = d_in[11];
  const void *wq2 = d_in[12], *bq2 = d_in[13];
  const void *wk2 = d_in[14], *bk2 = d_in[15];
  const void *wv2 = d_in[16], *bv2 = d_in[17];
  const void *wt2 = d_in[18], *bt2 = d_in[19];
  const void *wcp = d_in[20], *bcp = d_in[21];

  char* ws = (char*)d_ws;
  size_t off = 0;
  auto alloc = [&](size_t bytes) -> void* {
    void* p = ws + off;
    off += (bytes + 255) & ~(size_t)255;
    return p;
  };
  int*   flags  = (int*)alloc(256);
  float* divt   = (float*)alloc(256);
  u16*   WtBig  = (u16*)alloc((size_t)NB * HC * 2);
  float* biasBig= (float*)alloc((size_t)NB * 4);
  u16*   qkvp   = (u16*)alloc((size_t)NN * NB * 2);
  u16*   x1     = (u16*)alloc((size_t)NN * HC * 2);
  u16*   x2     = (u16*)alloc((size_t)NN * HC * 2);
  u16*   acast  = (u16*)alloc((size_t)NN * NIN * 2);
  float* ynode  = (float*)alloc((size_t)NN * 4);
  int* offsets  = (int*)alloc((size_t)(NN + 1) * 4);
  int* cursor   = (int*)alloc((size_t)NN * 4);
  int* bsum     = (int*)alloc(256 * 4);
  int* ssrc     = (int*)alloc((size_t)NE * 4);
  float* stt    = (float*)alloc((size_t)NE * 4);
  size_t need = off;

  int gN = (NN + 255) / 256, gE = (NE + 255) / 256;
  int nb = (NN + 255) / 256;

  if (ws_size < 1024) {
    raw_sentinel_kernel<<<gE, 256, 0, stream>>>((u16*)d_out);
    return;
  }
  devinit_kernel<<<1, 64, 0, stream>>>(eidx, nemb, flags, divt);
  if (need > ws_size) {
    sentinel_kernel<<<gE, 256, 0, stream>>>(flags, d_out);
    return;
  }

  // CSR by dst (+ sorted src / time)
  zero_kernel<<<gN, 256, 0, stream>>>(cursor, NN);
  hist_kernel<<<gE, 256, 0, stream>>>(flags, eidx, cursor);
  scan1_kernel<<<nb, 256, 0, stream>>>(cursor, offsets, bsum, NN);
  scan2_kernel<<<1, 256, 0, stream>>>(bsum, offsets, nb, NN);
  scan3_kernel<<<nb, 256, 0, stream>>>(offsets, bsum, cursor, NN);
  fill_kernel<<<gE, 256, 0, stream>>>(flags, eidx, rawt, noise, cursor, ssrc, stt);

  // A-cast for layer 1 (no-op if input already bf16)
  cast_kernel<<<(NN * NIN / 4 + 255) / 256, 256, 0, stream>>>(flags, nemb, acast);

  dim3 gt1(NIN / 64, 4, 3), gt2(HC / 64, 4, 3);

  // ---- Layer 1 (A = node_emb bf16, K=128) ----
  transw3_kernel<<<gt1, 256, 0, stream>>>(flags, wq1, wk1, wv1, WtBig, NIN);
  wcombbias_kernel<<<260, 256, 0, stream>>>(flags, wt1, WtBig, WtBig + (size_t)768 * NIN,
                                            bq1, bk1, bv1, biasBig, NIN);
  gemm_mfma<false><<<GEMM_BLOCKS, 256, 0, stream>>>(flags, nemb, acast, WtBig, biasBig,
                                                    qkvp, NN, NIN);
  aggfused_kernel<0><<<AGG_BLOCKS, 256, 0, stream>>>(flags, ssrc, offsets, stt, divt,
                                                     qkvp, bt1, x1, wcp, ynode);

  // ---- Layer 2 (A = bf16 x1, K=256) ----
  transw3_kernel<<<gt2, 256, 0, stream>>>(flags, wq2, wk2, wv2, WtBig, HC);
  wcombbias_kernel<<<260, 256, 0, stream>>>(flags, wt2, WtBig, WtBig + (size_t)768 * HC,
                                            bq2, bk2, bv2, biasBig, HC);
  gemm_mfma<true><<<GEMM_BLOCKS, 256, 0, stream>>>(flags, x1, (const u16*)0, WtBig, biasBig,
                                                   qkvp, NN, HC);
  aggfused_kernel<1><<<AGG_BLOCKS, 256, 0, stream>>>(flags, ssrc, offsets, stt, divt,
                                                     qkvp, bt2, x2, wcp, ynode);

  // Edge scorer epilogue
  final2_kernel<<<gE, 256, 0, stream>>>(flags, eidx, ynode, bcp, d_out);
}